// Round 15
// baseline (754.483 us; speedup 1.0000x reference)
//
#include <hip/hip_runtime.h>
#include <hip/hip_bf16.h>
#include <math.h>

#define HDIM 1024
#define NB 32
#define LA 2048
#define LO 32

typedef __attribute__((ext_vector_type(8))) short bf16x8;
typedef __attribute__((ext_vector_type(4))) float f32x4;
typedef unsigned int u32;

__device__ __forceinline__ float tanh_fast(float x){
    return 2.0f / (1.0f + __expf(-2.0f * x)) - 1.0f;
}

__device__ __forceinline__ void load_lds16(const void* gptr, void* lptr){
    __builtin_amdgcn_global_load_lds(
        (const __attribute__((address_space(1))) u32*)gptr,
        (__attribute__((address_space(3))) u32*)lptr, 16, 0, 0);
}

__device__ __forceinline__ void conv_range(const float* __restrict__ in,
                                           __hip_bfloat16* __restrict__ out,
                                           long n, int nblk, int lb){
    long i = ((long)lb * 256 + threadIdx.x) * 4;
    long stride = (long)nblk * 256 * 4;
    for (; i < n; i += stride){
        float4 v = *(const float4*)(in + i);
        union { __hip_bfloat16 h[4]; short4 s; } u;
        u.h[0] = __float2bfloat16(v.x); u.h[1] = __float2bfloat16(v.y);
        u.h[2] = __float2bfloat16(v.z); u.h[3] = __float2bfloat16(v.w);
        *(short4*)(out + i) = u.s;
    }
}

// ---- mega init: [0,1024) conv article | [1024,1056) zero | [1056,1568) proj_q
//      | [1568,1632) conv a_Kw | [1632,1696) conv d_Kw | [1696,2016) conv options
__global__ __launch_bounds__(256) void mega_init_kernel(
    const float* __restrict__ article, __hip_bfloat16* __restrict__ art_bf,
    float* __restrict__ zbase,
    const float* __restrict__ question, const int* __restrict__ ans,
    const float* __restrict__ a_Qw, const float* __restrict__ a_Qb,
    float* __restrict__ qp_a,
    const float* __restrict__ a_Kw, __hip_bfloat16* __restrict__ kwa_bf,
    const float* __restrict__ d_Kw, __hip_bfloat16* __restrict__ kwd_bf,
    const float* __restrict__ options, __hip_bfloat16* __restrict__ opt_bf)
{
    __shared__ float xin[HDIM];
    int bid = blockIdx.x;
    const int tid = threadIdx.x;
    if (bid < 1024){ conv_range(article, art_bf, 67108864L, 1024, bid); return; }
    bid -= 1024;
    if (bid < 32){
        int i = bid * 256 + tid;
        for (; i < 103424; i += 8192) zbase[i] = 0.f;
        return;
    }
    bid -= 32;
    if (bid < 512){
        const int g = bid >> 4, yq = bid & 15;
        const int lane = tid & 63, wave = tid >> 6;
        const float* in = question + ((size_t)g * 64 + ans[g]) * HDIM;
        *(float4*)&xin[tid * 4] = *(const float4*)&in[tid * 4];
        __syncthreads();
        float4 xv[4];
        #pragma unroll
        for (int c = 0; c < 4; c++) xv[c] = *(const float4*)&xin[(c * 64 + lane) * 4];
        const int hbase = yq * 64 + wave * 16;
        #pragma unroll 4
        for (int r = 0; r < 16; r++){
            int h = hbase + r;
            const float* Wr = a_Qw + (size_t)h * HDIM;
            float p = 0.f;
            #pragma unroll
            for (int c = 0; c < 4; c++){
                float4 wv = *(const float4*)&Wr[(c * 64 + lane) * 4];
                p = fmaf(xv[c].x, wv.x, p); p = fmaf(xv[c].y, wv.y, p);
                p = fmaf(xv[c].z, wv.z, p); p = fmaf(xv[c].w, wv.w, p);
            }
            #pragma unroll
            for (int off = 1; off < 64; off <<= 1) p += __shfl_xor(p, off, 64);
            if (lane == 0) qp_a[(size_t)g * HDIM + h] = p + a_Qb[h];
        }
        return;
    }
    bid -= 512;
    if (bid < 64){ conv_range(a_Kw, kwa_bf, 1048576L, 64, bid); return; }
    bid -= 64;
    if (bid < 64){ conv_range(d_Kw, kwd_bf, 1048576L, 64, bid); return; }
    bid -= 64;
    conv_range(options, opt_bf, 5242880L, 320, bid);
}

// ---- fused two-layer proj: block g: mid = a_Vw*w_art[g]+a_Vb (LDS only),
//      then qp_d[g] = d_Qw*mid + d_Qb. 4 waves x 256 rows each per layer.
__global__ __launch_bounds__(256) void proj2_kernel(
    const float* __restrict__ w_art,
    const float* __restrict__ a_Vw, const float* __restrict__ a_Vb,
    const float* __restrict__ d_Qw, const float* __restrict__ d_Qb,
    float* __restrict__ qp_d)
{
    __shared__ float xin[HDIM];
    __shared__ float mid[HDIM];
    const int g = blockIdx.x, tid = threadIdx.x;
    const int lane = tid & 63, wave = tid >> 6;
    *(float4*)&xin[tid * 4] = *(const float4*)&w_art[(size_t)g * HDIM + tid * 4];
    __syncthreads();
    float4 xv[4];
    #pragma unroll
    for (int c = 0; c < 4; c++) xv[c] = *(const float4*)&xin[(c * 64 + lane) * 4];
    for (int r = 0; r < 256; r++){
        int h = wave * 256 + r;
        const float* Wr = a_Vw + (size_t)h * HDIM;
        float p = 0.f;
        #pragma unroll
        for (int c = 0; c < 4; c++){
            float4 wv = *(const float4*)&Wr[(c * 64 + lane) * 4];
            p = fmaf(xv[c].x, wv.x, p); p = fmaf(xv[c].y, wv.y, p);
            p = fmaf(xv[c].z, wv.z, p); p = fmaf(xv[c].w, wv.w, p);
        }
        #pragma unroll
        for (int off = 1; off < 64; off <<= 1) p += __shfl_xor(p, off, 64);
        if (lane == 0) mid[h] = p + a_Vb[h];
    }
    __syncthreads();
    float4 yv[4];
    #pragma unroll
    for (int c = 0; c < 4; c++) yv[c] = *(const float4*)&mid[(c * 64 + lane) * 4];
    for (int r = 0; r < 256; r++){
        int h = wave * 256 + r;
        const float* Wr = d_Qw + (size_t)h * HDIM;
        float p = 0.f;
        #pragma unroll
        for (int c = 0; c < 4; c++){
            float4 wv = *(const float4*)&Wr[(c * 64 + lane) * 4];
            p = fmaf(yv[c].x, wv.x, p); p = fmaf(yv[c].y, wv.y, p);
            p = fmaf(yv[c].z, wv.z, p); p = fmaf(yv[c].w, wv.w, p);
        }
        #pragma unroll
        for (int off = 1; off < 64; off <<= 1) p += __shfl_xor(p, off, 64);
        if (lane == 0) qp_d[(size_t)g * HDIM + h] = p + d_Qb[h];
    }
}

// out[g,h] = bias[h] + dot(in[g,:], W[h,:])   grid (G, 16), block 256 (4 waves).
__global__ __launch_bounds__(256) void proj_kernel(
    const float* __restrict__ in, const float* __restrict__ W,
    const float* __restrict__ bias, float* __restrict__ out){
    __shared__ float xin[HDIM];
    const int g = blockIdx.x, tid = threadIdx.x;
    const int lane = tid & 63, wave = tid >> 6;
    *(float4*)&xin[tid * 4] = *(const float4*)&in[(size_t)g * HDIM + tid * 4];
    __syncthreads();
    float4 xv[4];
    #pragma unroll
    for (int c = 0; c < 4; c++) xv[c] = *(const float4*)&xin[(c * 64 + lane) * 4];
    const int hbase = blockIdx.y * 64 + wave * 16;
    #pragma unroll 4
    for (int r = 0; r < 16; r++){
        int h = hbase + r;
        const float* Wr = W + (size_t)h * HDIM;
        float p = 0.f;
        #pragma unroll
        for (int c = 0; c < 4; c++){
            float4 wv = *(const float4*)&Wr[(c * 64 + lane) * 4];
            p = fmaf(xv[c].x, wv.x, p); p = fmaf(xv[c].y, wv.y, p);
            p = fmaf(xv[c].z, wv.z, p); p = fmaf(xv[c].w, wv.w, p);
        }
        #pragma unroll
        for (int off = 1; off < 64; off <<= 1) p += __shfl_xor(p, off, 64);
        if (lane == 0) out[(size_t)g * HDIM + h] = p + bias[h];
    }
}

// ------------- 256h x 256a article score kernel (R14, verified) --------------
__global__ __launch_bounds__(512, 2) void score_mfma8p(
    const __hip_bfloat16* __restrict__ X, const __hip_bfloat16* __restrict__ Kw,
    const float* __restrict__ Kb, const float* __restrict__ Qp,
    const float* __restrict__ vw, float* __restrict__ s,
    int rows_per_batch)
{
    __shared__ __align__(16) char lds[131072];
    const int tid = threadIdx.x;
    const int lane = tid & 63, wid = tid >> 6;
    const int wm = wid >> 2, wn = wid & 3;
    const int lr = lane & 15, lg = lane >> 4;

    const int na = gridDim.x >> 2;
    const int bid = blockIdx.x;
    const int xcd = bid & 7, seq = bid >> 3;
    const int a_idx = xcd * (na >> 3) + (seq >> 2);
    const int h_idx = seq & 3;
    const int a0 = a_idx * 256, h0 = h_idx * 256;

    f32x4 acc[8][4] = {};
    bf16x8 av[8], bv[4];

    const int rA = tid >> 2;
    const int csw = ((tid & 3) * 16) ^ (((rA >> 1) & 3) << 4);
    const char* pA = (const char*)Kw + (size_t)(h0 + rA) * 2048 + csw;
    const char* pB = (const char*)X  + (size_t)(a0 + rA) * 2048 + csw;
    char* dst0 = lds + tid * 16;

    int aoff[8], boff[4];
    #pragma unroll
    for (int hf = 0; hf < 8; hf++){
        int rw = wm * 128 + hf * 16 + lr;
        aoff[hf] = rw * 64 + ((lg * 16) ^ (((rw >> 1) & 3) << 4));
    }
    #pragma unroll
    for (int af = 0; af < 4; af++){
        int rw = wn * 64 + af * 16 + lr;
        boff[af] = 16384 + rw * 64 + ((lg * 16) ^ (((rw >> 1) & 3) << 4));
    }

#define ISSUE_PAIR(j) do { \
    const int _base = (((j) >> 1) & 1) * 65536 + ((j) & 1) * 32768; \
    const size_t _ko = (size_t)(((j) >> 1) * 128 + ((j) & 1) * 64); \
    load_lds16(pA + _ko, dst0 + _base); \
    load_lds16(pA + _ko + 262144, dst0 + _base + 8192); \
    load_lds16(pB + _ko, dst0 + _base + 16384); \
    load_lds16(pB + _ko + 262144, dst0 + _base + 24576); } while(0)

#define READS_PAIR(k) do { \
    const int _base = (((k) >> 1) & 1) * 65536 + ((k) & 1) * 32768; \
    _Pragma("unroll") \
    for (int hf = 0; hf < 8; hf++) av[hf] = *(const bf16x8*)(lds + _base + aoff[hf]); \
    _Pragma("unroll") \
    for (int af = 0; af < 4; af++) bv[af] = *(const bf16x8*)(lds + _base + boff[af]); } while(0)

#define MFMA32() do { \
    asm volatile("s_waitcnt lgkmcnt(0)" ::: "memory"); \
    __builtin_amdgcn_sched_barrier(0); \
    __builtin_amdgcn_s_setprio(1); \
    _Pragma("unroll") \
    for (int hf = 0; hf < 8; hf++) \
        _Pragma("unroll") \
        for (int af = 0; af < 4; af++) \
            acc[hf][af] = __builtin_amdgcn_mfma_f32_16x16x32_bf16(av[hf], bv[af], acc[hf][af], 0, 0, 0); \
    __builtin_amdgcn_s_setprio(0); } while(0)

    ISSUE_PAIR(0); ISSUE_PAIR(1); ISSUE_PAIR(2);

    #pragma unroll 2
    for (int k = 0; k < 29; ++k){
        asm volatile("s_waitcnt vmcnt(8)" ::: "memory");
        __builtin_amdgcn_s_barrier();
        ISSUE_PAIR(k + 3);
        READS_PAIR(k);
        MFMA32();
    }
    {
        asm volatile("s_waitcnt vmcnt(8)" ::: "memory");
        __builtin_amdgcn_s_barrier();
        READS_PAIR(29);
        MFMA32();
    }
    {
        asm volatile("s_waitcnt vmcnt(4)" ::: "memory");
        __builtin_amdgcn_s_barrier();
        READS_PAIR(30);
        MFMA32();
    }
    {
        asm volatile("s_waitcnt vmcnt(0)" ::: "memory");
        __builtin_amdgcn_s_barrier();
        READS_PAIR(31);
        MFMA32();
    }

    const int b = a0 / rows_per_batch;
    float part[4] = {0.f, 0.f, 0.f, 0.f};
    #pragma unroll
    for (int hf = 0; hf < 8; hf++){
        int hbase = h0 + wm * 128 + hf * 16 + lg * 4;
        float4 kb4 = *(const float4*)(Kb + hbase);
        float4 qp4 = *(const float4*)(Qp + (size_t)b * HDIM + hbase);
        float4 vw4 = *(const float4*)(vw + hbase);
        float q0v = kb4.x + qp4.x, q1v = kb4.y + qp4.y;
        float q2v = kb4.z + qp4.z, q3v = kb4.w + qp4.w;
        #pragma unroll
        for (int af = 0; af < 4; af++){
            part[af] += tanh_fast(acc[hf][af][0] + q0v) * vw4.x;
            part[af] += tanh_fast(acc[hf][af][1] + q1v) * vw4.y;
            part[af] += tanh_fast(acc[hf][af][2] + q2v) * vw4.z;
            part[af] += tanh_fast(acc[hf][af][3] + q3v) * vw4.w;
        }
    }
    #pragma unroll
    for (int af = 0; af < 4; af++){
        float p = part[af];
        p += __shfl_xor(p, 16, 64);
        p += __shfl_xor(p, 32, 64);
        if (lane < 16)
            atomicAdd(&s[a0 + wn * 64 + af * 16 + lr], p);
    }
#undef ISSUE_PAIR
#undef READS_PAIR
#undef MFMA32
}

// ---------------- old 128x128 4-wave score kernel (option path) --------------
#define SBM 128
#define SBN 128
__global__ __launch_bounds__(256) void score_mfma_kernel(
    const __hip_bfloat16* __restrict__ X, const __hip_bfloat16* __restrict__ Kw,
    const float* __restrict__ Kb, const float* __restrict__ Qp,
    const float* __restrict__ vw, float* __restrict__ s,
    int row_off, int rows_per_batch)
{
    __shared__ __align__(16) __hip_bfloat16 As[SBM][32];
    __shared__ __align__(16) __hip_bfloat16 Bs[SBN][32];
    const int tid = threadIdx.x;
    const int lane = tid & 63, wid = tid >> 6;
    const int wm = wid >> 1, wn = wid & 1;
    const int row0 = blockIdx.x * SBM;
    const int h0 = blockIdx.y * SBN;
    const int lr = lane & 15, lg = lane >> 4;

    f32x4 acc[4][4] = {};

    for (int k0 = 0; k0 < HDIM; k0 += 32){
        #pragma unroll
        for (int l = 0; l < 2; l++){
            int f = tid + l * 256;
            int r = f >> 2, c8 = (f & 3) * 8;
            load_lds16(X + (size_t)(row0 + r) * HDIM + k0 + c8, &As[0][0] + f * 8);
            load_lds16(Kw + (size_t)(h0 + r) * HDIM + k0 + c8, &Bs[0][0] + f * 8);
        }
        __syncthreads();
        bf16x8 a[4], b[4];
        #pragma unroll
        for (int i = 0; i < 4; i++)
            a[i] = *(const bf16x8*)&As[wm * 64 + i * 16 + lr][lg * 8];
        #pragma unroll
        for (int j = 0; j < 4; j++)
            b[j] = *(const bf16x8*)&Bs[wn * 64 + j * 16 + lr][lg * 8];
        #pragma unroll
        for (int i = 0; i < 4; i++)
            #pragma unroll
            for (int j = 0; j < 4; j++)
                acc[i][j] = __builtin_amdgcn_mfma_f32_16x16x32_bf16(a[i], b[j], acc[i][j], 0, 0, 0);
        __syncthreads();
    }

    float kbv[4], vwv[4];
    #pragma unroll
    for (int j = 0; j < 4; j++){
        int h = h0 + wn * 64 + j * 16 + lr;
        kbv[j] = Kb[h]; vwv[j] = vw[h];
    }
    #pragma unroll
    for (int i = 0; i < 4; i++){
        #pragma unroll
        for (int reg = 0; reg < 4; reg++){
            int r = row0 + wm * 64 + i * 16 + lg * 4 + reg;
            int gr = row_off + r;
            int bb = gr / rows_per_batch;
            const float* Qpb = Qp + (size_t)bb * HDIM;
            float p = 0.f;
            #pragma unroll
            for (int j = 0; j < 4; j++){
                int h = h0 + wn * 64 + j * 16 + lr;
                p += tanh_fast(acc[i][j][reg] + kbv[j] + Qpb[h]) * vwv[j];
            }
            #pragma unroll
            for (int off = 1; off < 16; off <<= 1) p += __shfl_xor(p, off, 16);
            if (lr == 0) atomicAdd(&s[gr], p);
        }
    }
}

// in-place softmax over groups of Rg, grid = G blocks of 256
__global__ void softmax_kernel(float* __restrict__ s, int Rg){
    __shared__ float red[4];
    int g = blockIdx.x, tid = threadIdx.x;
    float* sg = s + (size_t)g * Rg;
    float m = -INFINITY;
    for (int i = tid; i < Rg; i += 256) m = fmaxf(m, sg[i]);
    #pragma unroll
    for (int off = 32; off > 0; off >>= 1) m = fmaxf(m, __shfl_down(m, off, 64));
    if ((tid & 63) == 0) red[tid >> 6] = m;
    __syncthreads();
    m = fmaxf(fmaxf(red[0], red[1]), fmaxf(red[2], red[3]));
    __syncthreads();
    float sum = 0.f;
    for (int i = tid; i < Rg; i += 256){ float e = __expf(sg[i] - m); sg[i] = e; sum += e; }
    #pragma unroll
    for (int off = 32; off > 0; off >>= 1) sum += __shfl_down(sum, off, 64);
    if ((tid & 63) == 0) red[tid >> 6] = sum;
    __syncthreads();
    float inv = 1.0f / (red[0] + red[1] + red[2] + red[3]);
    for (int i = tid; i < Rg; i += 256) sg[i] *= inv;
}

// vectorized bf16 weighted sum (article): grid (NB, 8), 256 thr, short4/thread
__global__ __launch_bounds__(256) void wsum_art_v(
    const __hip_bfloat16* __restrict__ X, const float* __restrict__ sc,
    float* __restrict__ out){
    __shared__ float scs[256];
    const int g = blockIdx.x, ic = blockIdx.y, tid = threadIdx.x;
    scs[tid] = sc[(size_t)g * LA + ic * 256 + tid];
    __syncthreads();
    const __hip_bfloat16* Xg = X + ((size_t)g * LA + ic * 256) * HDIM + tid * 4;
    float a0 = 0.f, a1 = 0.f, a2 = 0.f, a3 = 0.f;
    for (int i = 0; i < 256; i++){
        short4 v = *(const short4*)(Xg + (size_t)i * HDIM);
        float w = scs[i];
        a0 = fmaf(w, __bfloat162float(*(const __hip_bfloat16*)&v.x), a0);
        a1 = fmaf(w, __bfloat162float(*(const __hip_bfloat16*)&v.y), a1);
        a2 = fmaf(w, __bfloat162float(*(const __hip_bfloat16*)&v.z), a2);
        a3 = fmaf(w, __bfloat162float(*(const __hip_bfloat16*)&v.w), a3);
    }
    float* o = out + (size_t)g * HDIM + tid * 4;
    atomicAdd(o + 0, a0); atomicAdd(o + 1, a1);
    atomicAdd(o + 2, a2); atomicAdd(o + 3, a3);
}

// fused 32-softmax + weighted sum (options): grid 160, direct store
__global__ __launch_bounds__(256) void wsum_opt_sm(
    const __hip_bfloat16* __restrict__ X, const float* __restrict__ sraw,
    float* __restrict__ out){
    __shared__ float raw[LO], scs[LO];
    const int g = blockIdx.x, tid = threadIdx.x;
    if (tid < LO) raw[tid] = sraw[(size_t)g * LO + tid];
    __syncthreads();
    float m = -INFINITY;
    #pragma unroll
    for (int i = 0; i < LO; i++) m = fmaxf(m, raw[i]);
    float ssum = 0.f;
    #pragma unroll
    for (int i = 0; i < LO; i++) ssum += __expf(raw[i] - m);
    if (tid < LO) scs[tid] = __expf(raw[tid] - m) / ssum;
    __syncthreads();
    const __hip_bfloat16* Xg = X + (size_t)g * LO * HDIM + tid * 4;
    float a0 = 0.f, a1 = 0.f, a2 = 0.f, a3 = 0.f;
    for (int i = 0; i < LO; i++){
        short4 v = *(const short4*)(Xg + (size_t)i * HDIM);
        float w = scs[i];
        a0 = fmaf(w, __bfloat162float(*(const __hip_bfloat16*)&v.x), a0);
        a1 = fmaf(w, __bfloat162float(*(const __hip_bfloat16*)&v.y), a1);
        a2 = fmaf(w, __bfloat162float(*(const __hip_bfloat16*)&v.z), a2);
        a3 = fmaf(w, __bfloat162float(*(const __hip_bfloat16*)&v.w), a3);
    }
    float* o = out + (size_t)g * HDIM + tid * 4;
    o[0] = a0; o[1] = a1; o[2] = a2; o[3] = a3;
}

// logits[b,j] = fb[j] + dot(feats[b,:5120], fw[j,:5120])  grid 32, block 256
__global__ void final_kernel(const float* __restrict__ feats, const float* __restrict__ fw,
                             const float* __restrict__ fb, float* __restrict__ out){
    __shared__ float red[4];
    int b = blockIdx.x, tid = threadIdx.x;
    const float* fe = feats + (size_t)b * 5120;
    for (int j = 0; j < 5; j++){
        float acc = 0.f;
        for (int i = tid; i < 5120; i += 256) acc += fe[i] * fw[(size_t)j * 5120 + i];
        #pragma unroll
        for (int off = 32; off > 0; off >>= 1) acc += __shfl_down(acc, off, 64);
        if ((tid & 63) == 0) red[tid >> 6] = acc;
        __syncthreads();
        if (tid == 0) out[b * 5 + j] = fb[j] + red[0] + red[1] + red[2] + red[3];
        __syncthreads();
    }
}

extern "C" void kernel_launch(void* const* d_in, const int* in_sizes, int n_in,
                              void* d_out, int out_size, void* d_ws, size_t ws_size,
                              hipStream_t stream) {
    const float* article  = (const float*)d_in[0];
    const float* question = (const float*)d_in[1];
    const float* options  = (const float*)d_in[2];
    const int*   ans      = (const int*)d_in[3];
    const float* a_Qw = (const float*)d_in[4];  const float* a_Qb = (const float*)d_in[5];
    const float* a_Kw = (const float*)d_in[6];  const float* a_Kb = (const float*)d_in[7];
    const float* a_Vw = (const float*)d_in[8];  const float* a_Vb = (const float*)d_in[9];
    const float* a_vw = (const float*)d_in[10];
    const float* d_Qw = (const float*)d_in[12]; const float* d_Qb = (const float*)d_in[13];
    const float* d_Kw = (const float*)d_in[14]; const float* d_Kb = (const float*)d_in[15];
    const float* d_Vw = (const float*)d_in[16]; const float* d_Vb = (const float*)d_in[17];
    const float* d_vw = (const float*)d_in[18];
    const float* f_w  = (const float*)d_in[20]; const float* f_b  = (const float*)d_in[21];
    float* out = (float*)d_out;

    float* ws = (float*)d_ws;
    float* qp_a  = ws + 32768;       // 32768
    float* qp_d  = ws + 98304;       // 32768
    float* feats = ws + 131072;      // 163840
    float* s_art = ws + 294912;      // 65536  (zeroed)
    float* s_opt = ws + 360448;      // 5120   (zeroed)
    float* w_art = ws + 365568;      // 32768  (zeroed)
    float* wd    = ws + 398336;      // 163840 (direct-store, no zero)
    // bf16 region
    __hip_bfloat16* kwa_bf = (__hip_bfloat16*)(ws + 562176);
    __hip_bfloat16* kwd_bf = kwa_bf + 1048576;
    __hip_bfloat16* opt_bf = kwd_bf + 1048576;       // 5242880 elems
    __hip_bfloat16* art_bf = opt_bf + 5242880;       // 67108864 elems

    // K1: all independent init work (conv article first = long pole)
    mega_init_kernel<<<2016, 256, 0, stream>>>(
        article, art_bf, s_art,
        question, ans, a_Qw, a_Qb, qp_a,
        a_Kw, kwa_bf, d_Kw, kwd_bf, options, opt_bf);
    // K2: article score GEMM
    score_mfma8p<<<(NB * LA / 256) * 4, 512, 0, stream>>>(
        art_bf, kwa_bf, a_Kb, qp_a, a_vw, s_art, LA);
    // K3: article softmax
    softmax_kernel<<<NB, 256, 0, stream>>>(s_art, LA);
    // K4: article weighted sum
    wsum_art_v<<<dim3(NB, 8), 256, 0, stream>>>(art_bf, s_art, w_art);
    // K5: fused aq + qp_d projections
    proj2_kernel<<<NB, 256, 0, stream>>>(w_art, a_Vw, a_Vb, d_Qw, d_Qb, qp_d);
    // K6: option score GEMM
    score_mfma_kernel<<<dim3((NB * 5 * LO) / SBM, HDIM / SBN), 256, 0, stream>>>(
        opt_bf, kwd_bf, d_Kb, qp_d, d_vw, s_opt, 0, 5 * LO);
    // K7: fused option softmax + weighted sum
    wsum_opt_sm<<<NB * 5, 256, 0, stream>>>(opt_bf, s_opt, wd);
    // K8: option V projection -> feats
    proj_kernel<<<dim3(NB * 5, 16), 256, 0, stream>>>(wd, d_Vw, d_Vb, feats);
    // K9: final logits
    final_kernel<<<NB, 256, 0, stream>>>(feats, f_w, f_b, out);
}

// Round 16
// 399.654 us; speedup vs baseline: 1.8878x; 1.8878x over previous
//
#include <hip/hip_runtime.h>
#include <hip/hip_bf16.h>
#include <math.h>

#define HDIM 1024
#define NB 32
#define LA 2048
#define LO 32

typedef __attribute__((ext_vector_type(8))) short bf16x8;
typedef __attribute__((ext_vector_type(4))) float f32x4;
typedef unsigned int u32;

__device__ __forceinline__ float tanh_fast(float x){
    return 2.0f / (1.0f + __expf(-2.0f * x)) - 1.0f;
}

__device__ __forceinline__ void load_lds16(const void* gptr, void* lptr){
    __builtin_amdgcn_global_load_lds(
        (const __attribute__((address_space(1))) u32*)gptr,
        (__attribute__((address_space(3))) u32*)lptr, 16, 0, 0);
}

__device__ __forceinline__ void conv_range(const float* __restrict__ in,
                                           __hip_bfloat16* __restrict__ out,
                                           long n, int nblk, int lb){
    long i = ((long)lb * 256 + threadIdx.x) * 4;
    long stride = (long)nblk * 256 * 4;
    for (; i < n; i += stride){
        float4 v = *(const float4*)(in + i);
        union { __hip_bfloat16 h[4]; short4 s; } u;
        u.h[0] = __float2bfloat16(v.x); u.h[1] = __float2bfloat16(v.y);
        u.h[2] = __float2bfloat16(v.z); u.h[3] = __float2bfloat16(v.w);
        *(short4*)(out + i) = u.s;
    }
}

// ---- mega init: [0,1024) conv article | [1024,1056) zero | [1056,1568) proj_q
//      | [1568,1632) conv a_Kw | [1632,1696) conv d_Kw | [1696,2016) conv options
__global__ __launch_bounds__(256) void mega_init_kernel(
    const float* __restrict__ article, __hip_bfloat16* __restrict__ art_bf,
    float* __restrict__ zbase,
    const float* __restrict__ question, const int* __restrict__ ans,
    const float* __restrict__ a_Qw, const float* __restrict__ a_Qb,
    float* __restrict__ qp_a,
    const float* __restrict__ a_Kw, __hip_bfloat16* __restrict__ kwa_bf,
    const float* __restrict__ d_Kw, __hip_bfloat16* __restrict__ kwd_bf,
    const float* __restrict__ options, __hip_bfloat16* __restrict__ opt_bf)
{
    __shared__ float xin[HDIM];
    int bid = blockIdx.x;
    const int tid = threadIdx.x;
    if (bid < 1024){ conv_range(article, art_bf, 67108864L, 1024, bid); return; }
    bid -= 1024;
    if (bid < 32){
        int i = bid * 256 + tid;
        for (; i < 103424; i += 8192) zbase[i] = 0.f;
        return;
    }
    bid -= 32;
    if (bid < 512){
        const int g = bid >> 4, yq = bid & 15;
        const int lane = tid & 63, wave = tid >> 6;
        const float* in = question + ((size_t)g * 64 + ans[g]) * HDIM;
        *(float4*)&xin[tid * 4] = *(const float4*)&in[tid * 4];
        __syncthreads();
        float4 xv[4];
        #pragma unroll
        for (int c = 0; c < 4; c++) xv[c] = *(const float4*)&xin[(c * 64 + lane) * 4];
        const int hbase = yq * 64 + wave * 16;
        #pragma unroll 4
        for (int r = 0; r < 16; r++){
            int h = hbase + r;
            const float* Wr = a_Qw + (size_t)h * HDIM;
            float p = 0.f;
            #pragma unroll
            for (int c = 0; c < 4; c++){
                float4 wv = *(const float4*)&Wr[(c * 64 + lane) * 4];
                p = fmaf(xv[c].x, wv.x, p); p = fmaf(xv[c].y, wv.y, p);
                p = fmaf(xv[c].z, wv.z, p); p = fmaf(xv[c].w, wv.w, p);
            }
            #pragma unroll
            for (int off = 1; off < 64; off <<= 1) p += __shfl_xor(p, off, 64);
            if (lane == 0) qp_a[(size_t)g * HDIM + h] = p + a_Qb[h];
        }
        return;
    }
    bid -= 512;
    if (bid < 64){ conv_range(a_Kw, kwa_bf, 1048576L, 64, bid); return; }
    bid -= 64;
    if (bid < 64){ conv_range(d_Kw, kwd_bf, 1048576L, 64, bid); return; }
    bid -= 64;
    conv_range(options, opt_bf, 5242880L, 320, bid);
}

// out[g,h] = bias[h] + dot(in[g,:], W[h,:])   grid (G, 16), block 256 (4 waves).
__global__ __launch_bounds__(256) void proj_kernel(
    const float* __restrict__ in, const float* __restrict__ W,
    const float* __restrict__ bias, float* __restrict__ out){
    __shared__ float xin[HDIM];
    const int g = blockIdx.x, tid = threadIdx.x;
    const int lane = tid & 63, wave = tid >> 6;
    *(float4*)&xin[tid * 4] = *(const float4*)&in[(size_t)g * HDIM + tid * 4];
    __syncthreads();
    float4 xv[4];
    #pragma unroll
    for (int c = 0; c < 4; c++) xv[c] = *(const float4*)&xin[(c * 64 + lane) * 4];
    const int hbase = blockIdx.y * 64 + wave * 16;
    #pragma unroll 4
    for (int r = 0; r < 16; r++){
        int h = hbase + r;
        const float* Wr = W + (size_t)h * HDIM;
        float p = 0.f;
        #pragma unroll
        for (int c = 0; c < 4; c++){
            float4 wv = *(const float4*)&Wr[(c * 64 + lane) * 4];
            p = fmaf(xv[c].x, wv.x, p); p = fmaf(xv[c].y, wv.y, p);
            p = fmaf(xv[c].z, wv.z, p); p = fmaf(xv[c].w, wv.w, p);
        }
        #pragma unroll
        for (int off = 1; off < 64; off <<= 1) p += __shfl_xor(p, off, 64);
        if (lane == 0) out[(size_t)g * HDIM + h] = p + bias[h];
    }
}

// ------------- 256h x 256a article score kernel (R14, verified) --------------
__global__ __launch_bounds__(512, 2) void score_mfma8p(
    const __hip_bfloat16* __restrict__ X, const __hip_bfloat16* __restrict__ Kw,
    const float* __restrict__ Kb, const float* __restrict__ Qp,
    const float* __restrict__ vw, float* __restrict__ s,
    int rows_per_batch)
{
    __shared__ __align__(16) char lds[131072];
    const int tid = threadIdx.x;
    const int lane = tid & 63, wid = tid >> 6;
    const int wm = wid >> 2, wn = wid & 3;
    const int lr = lane & 15, lg = lane >> 4;

    const int na = gridDim.x >> 2;
    const int bid = blockIdx.x;
    const int xcd = bid & 7, seq = bid >> 3;
    const int a_idx = xcd * (na >> 3) + (seq >> 2);
    const int h_idx = seq & 3;
    const int a0 = a_idx * 256, h0 = h_idx * 256;

    f32x4 acc[8][4] = {};
    bf16x8 av[8], bv[4];

    const int rA = tid >> 2;
    const int csw = ((tid & 3) * 16) ^ (((rA >> 1) & 3) << 4);
    const char* pA = (const char*)Kw + (size_t)(h0 + rA) * 2048 + csw;
    const char* pB = (const char*)X  + (size_t)(a0 + rA) * 2048 + csw;
    char* dst0 = lds + tid * 16;

    int aoff[8], boff[4];
    #pragma unroll
    for (int hf = 0; hf < 8; hf++){
        int rw = wm * 128 + hf * 16 + lr;
        aoff[hf] = rw * 64 + ((lg * 16) ^ (((rw >> 1) & 3) << 4));
    }
    #pragma unroll
    for (int af = 0; af < 4; af++){
        int rw = wn * 64 + af * 16 + lr;
        boff[af] = 16384 + rw * 64 + ((lg * 16) ^ (((rw >> 1) & 3) << 4));
    }

#define ISSUE_PAIR(j) do { \
    const int _base = (((j) >> 1) & 1) * 65536 + ((j) & 1) * 32768; \
    const size_t _ko = (size_t)(((j) >> 1) * 128 + ((j) & 1) * 64); \
    load_lds16(pA + _ko, dst0 + _base); \
    load_lds16(pA + _ko + 262144, dst0 + _base + 8192); \
    load_lds16(pB + _ko, dst0 + _base + 16384); \
    load_lds16(pB + _ko + 262144, dst0 + _base + 24576); } while(0)

#define READS_PAIR(k) do { \
    const int _base = (((k) >> 1) & 1) * 65536 + ((k) & 1) * 32768; \
    _Pragma("unroll") \
    for (int hf = 0; hf < 8; hf++) av[hf] = *(const bf16x8*)(lds + _base + aoff[hf]); \
    _Pragma("unroll") \
    for (int af = 0; af < 4; af++) bv[af] = *(const bf16x8*)(lds + _base + boff[af]); } while(0)

#define MFMA32() do { \
    asm volatile("s_waitcnt lgkmcnt(0)" ::: "memory"); \
    __builtin_amdgcn_sched_barrier(0); \
    __builtin_amdgcn_s_setprio(1); \
    _Pragma("unroll") \
    for (int hf = 0; hf < 8; hf++) \
        _Pragma("unroll") \
        for (int af = 0; af < 4; af++) \
            acc[hf][af] = __builtin_amdgcn_mfma_f32_16x16x32_bf16(av[hf], bv[af], acc[hf][af], 0, 0, 0); \
    __builtin_amdgcn_s_setprio(0); } while(0)

    ISSUE_PAIR(0); ISSUE_PAIR(1); ISSUE_PAIR(2);

    #pragma unroll 2
    for (int k = 0; k < 29; ++k){
        asm volatile("s_waitcnt vmcnt(8)" ::: "memory");
        __builtin_amdgcn_s_barrier();
        ISSUE_PAIR(k + 3);
        READS_PAIR(k);
        MFMA32();
    }
    {
        asm volatile("s_waitcnt vmcnt(8)" ::: "memory");
        __builtin_amdgcn_s_barrier();
        READS_PAIR(29);
        MFMA32();
    }
    {
        asm volatile("s_waitcnt vmcnt(4)" ::: "memory");
        __builtin_amdgcn_s_barrier();
        READS_PAIR(30);
        MFMA32();
    }
    {
        asm volatile("s_waitcnt vmcnt(0)" ::: "memory");
        __builtin_amdgcn_s_barrier();
        READS_PAIR(31);
        MFMA32();
    }

    const int b = a0 / rows_per_batch;
    float part[4] = {0.f, 0.f, 0.f, 0.f};
    #pragma unroll
    for (int hf = 0; hf < 8; hf++){
        int hbase = h0 + wm * 128 + hf * 16 + lg * 4;
        float4 kb4 = *(const float4*)(Kb + hbase);
        float4 qp4 = *(const float4*)(Qp + (size_t)b * HDIM + hbase);
        float4 vw4 = *(const float4*)(vw + hbase);
        float q0v = kb4.x + qp4.x, q1v = kb4.y + qp4.y;
        float q2v = kb4.z + qp4.z, q3v = kb4.w + qp4.w;
        #pragma unroll
        for (int af = 0; af < 4; af++){
            part[af] += tanh_fast(acc[hf][af][0] + q0v) * vw4.x;
            part[af] += tanh_fast(acc[hf][af][1] + q1v) * vw4.y;
            part[af] += tanh_fast(acc[hf][af][2] + q2v) * vw4.z;
            part[af] += tanh_fast(acc[hf][af][3] + q3v) * vw4.w;
        }
    }
    #pragma unroll
    for (int af = 0; af < 4; af++){
        float p = part[af];
        p += __shfl_xor(p, 16, 64);
        p += __shfl_xor(p, 32, 64);
        if (lane < 16)
            atomicAdd(&s[a0 + wn * 64 + af * 16 + lr], p);
    }
#undef ISSUE_PAIR
#undef READS_PAIR
#undef MFMA32
}

// ---------------- old 128x128 4-wave score kernel (option path) --------------
#define SBM 128
#define SBN 128
__global__ __launch_bounds__(256) void score_mfma_kernel(
    const __hip_bfloat16* __restrict__ X, const __hip_bfloat16* __restrict__ Kw,
    const float* __restrict__ Kb, const float* __restrict__ Qp,
    const float* __restrict__ vw, float* __restrict__ s,
    int row_off, int rows_per_batch)
{
    __shared__ __align__(16) __hip_bfloat16 As[SBM][32];
    __shared__ __align__(16) __hip_bfloat16 Bs[SBN][32];
    const int tid = threadIdx.x;
    const int lane = tid & 63, wid = tid >> 6;
    const int wm = wid >> 1, wn = wid & 1;
    const int row0 = blockIdx.x * SBM;
    const int h0 = blockIdx.y * SBN;
    const int lr = lane & 15, lg = lane >> 4;

    f32x4 acc[4][4] = {};

    for (int k0 = 0; k0 < HDIM; k0 += 32){
        #pragma unroll
        for (int l = 0; l < 2; l++){
            int f = tid + l * 256;
            int r = f >> 2, c8 = (f & 3) * 8;
            load_lds16(X + (size_t)(row0 + r) * HDIM + k0 + c8, &As[0][0] + f * 8);
            load_lds16(Kw + (size_t)(h0 + r) * HDIM + k0 + c8, &Bs[0][0] + f * 8);
        }
        __syncthreads();
        bf16x8 a[4], b[4];
        #pragma unroll
        for (int i = 0; i < 4; i++)
            a[i] = *(const bf16x8*)&As[wm * 64 + i * 16 + lr][lg * 8];
        #pragma unroll
        for (int j = 0; j < 4; j++)
            b[j] = *(const bf16x8*)&Bs[wn * 64 + j * 16 + lr][lg * 8];
        #pragma unroll
        for (int i = 0; i < 4; i++)
            #pragma unroll
            for (int j = 0; j < 4; j++)
                acc[i][j] = __builtin_amdgcn_mfma_f32_16x16x32_bf16(a[i], b[j], acc[i][j], 0, 0, 0);
        __syncthreads();
    }

    float kbv[4], vwv[4];
    #pragma unroll
    for (int j = 0; j < 4; j++){
        int h = h0 + wn * 64 + j * 16 + lr;
        kbv[j] = Kb[h]; vwv[j] = vw[h];
    }
    #pragma unroll
    for (int i = 0; i < 4; i++){
        #pragma unroll
        for (int reg = 0; reg < 4; reg++){
            int r = row0 + wm * 64 + i * 16 + lg * 4 + reg;
            int gr = row_off + r;
            int bb = gr / rows_per_batch;
            const float* Qpb = Qp + (size_t)bb * HDIM;
            float p = 0.f;
            #pragma unroll
            for (int j = 0; j < 4; j++){
                int h = h0 + wn * 64 + j * 16 + lr;
                p += tanh_fast(acc[i][j][reg] + kbv[j] + Qpb[h]) * vwv[j];
            }
            #pragma unroll
            for (int off = 1; off < 16; off <<= 1) p += __shfl_xor(p, off, 16);
            if (lr == 0) atomicAdd(&s[gr], p);
        }
    }
}

// in-place softmax over groups of Rg, grid = G blocks of 256
__global__ void softmax_kernel(float* __restrict__ s, int Rg){
    __shared__ float red[4];
    int g = blockIdx.x, tid = threadIdx.x;
    float* sg = s + (size_t)g * Rg;
    float m = -INFINITY;
    for (int i = tid; i < Rg; i += 256) m = fmaxf(m, sg[i]);
    #pragma unroll
    for (int off = 32; off > 0; off >>= 1) m = fmaxf(m, __shfl_down(m, off, 64));
    if ((tid & 63) == 0) red[tid >> 6] = m;
    __syncthreads();
    m = fmaxf(fmaxf(red[0], red[1]), fmaxf(red[2], red[3]));
    __syncthreads();
    float sum = 0.f;
    for (int i = tid; i < Rg; i += 256){ float e = __expf(sg[i] - m); sg[i] = e; sum += e; }
    #pragma unroll
    for (int off = 32; off > 0; off >>= 1) sum += __shfl_down(sum, off, 64);
    if ((tid & 63) == 0) red[tid >> 6] = sum;
    __syncthreads();
    float inv = 1.0f / (red[0] + red[1] + red[2] + red[3]);
    for (int i = tid; i < Rg; i += 256) sg[i] *= inv;
}

// vectorized bf16 weighted sum (article): grid (NB, 8), 256 thr, short4/thread
__global__ __launch_bounds__(256) void wsum_art_v(
    const __hip_bfloat16* __restrict__ X, const float* __restrict__ sc,
    float* __restrict__ out){
    __shared__ float scs[256];
    const int g = blockIdx.x, ic = blockIdx.y, tid = threadIdx.x;
    scs[tid] = sc[(size_t)g * LA + ic * 256 + tid];
    __syncthreads();
    const __hip_bfloat16* Xg = X + ((size_t)g * LA + ic * 256) * HDIM + tid * 4;
    float a0 = 0.f, a1 = 0.f, a2 = 0.f, a3 = 0.f;
    for (int i = 0; i < 256; i++){
        short4 v = *(const short4*)(Xg + (size_t)i * HDIM);
        float w = scs[i];
        a0 = fmaf(w, __bfloat162float(*(const __hip_bfloat16*)&v.x), a0);
        a1 = fmaf(w, __bfloat162float(*(const __hip_bfloat16*)&v.y), a1);
        a2 = fmaf(w, __bfloat162float(*(const __hip_bfloat16*)&v.z), a2);
        a3 = fmaf(w, __bfloat162float(*(const __hip_bfloat16*)&v.w), a3);
    }
    float* o = out + (size_t)g * HDIM + tid * 4;
    atomicAdd(o + 0, a0); atomicAdd(o + 1, a1);
    atomicAdd(o + 2, a2); atomicAdd(o + 3, a3);
}

// fused 32-softmax + weighted sum (options): grid 160, direct store
__global__ __launch_bounds__(256) void wsum_opt_sm(
    const __hip_bfloat16* __restrict__ X, const float* __restrict__ sraw,
    float* __restrict__ out){
    __shared__ float raw[LO], scs[LO];
    const int g = blockIdx.x, tid = threadIdx.x;
    if (tid < LO) raw[tid] = sraw[(size_t)g * LO + tid];
    __syncthreads();
    float m = -INFINITY;
    #pragma unroll
    for (int i = 0; i < LO; i++) m = fmaxf(m, raw[i]);
    float ssum = 0.f;
    #pragma unroll
    for (int i = 0; i < LO; i++) ssum += __expf(raw[i] - m);
    if (tid < LO) scs[tid] = __expf(raw[tid] - m) / ssum;
    __syncthreads();
    const __hip_bfloat16* Xg = X + (size_t)g * LO * HDIM + tid * 4;
    float a0 = 0.f, a1 = 0.f, a2 = 0.f, a3 = 0.f;
    for (int i = 0; i < LO; i++){
        short4 v = *(const short4*)(Xg + (size_t)i * HDIM);
        float w = scs[i];
        a0 = fmaf(w, __bfloat162float(*(const __hip_bfloat16*)&v.x), a0);
        a1 = fmaf(w, __bfloat162float(*(const __hip_bfloat16*)&v.y), a1);
        a2 = fmaf(w, __bfloat162float(*(const __hip_bfloat16*)&v.z), a2);
        a3 = fmaf(w, __bfloat162float(*(const __hip_bfloat16*)&v.w), a3);
    }
    float* o = out + (size_t)g * HDIM + tid * 4;
    o[0] = a0; o[1] = a1; o[2] = a2; o[3] = a3;
}

// logits[b,j] = fb[j] + dot(feats[b,:5120], fw[j,:5120])  grid 32, block 256
__global__ void final_kernel(const float* __restrict__ feats, const float* __restrict__ fw,
                             const float* __restrict__ fb, float* __restrict__ out){
    __shared__ float red[4];
    int b = blockIdx.x, tid = threadIdx.x;
    const float* fe = feats + (size_t)b * 5120;
    for (int j = 0; j < 5; j++){
        float acc = 0.f;
        for (int i = tid; i < 5120; i += 256) acc += fe[i] * fw[(size_t)j * 5120 + i];
        #pragma unroll
        for (int off = 32; off > 0; off >>= 1) acc += __shfl_down(acc, off, 64);
        if ((tid & 63) == 0) red[tid >> 6] = acc;
        __syncthreads();
        if (tid == 0) out[b * 5 + j] = fb[j] + red[0] + red[1] + red[2] + red[3];
        __syncthreads();
    }
}

extern "C" void kernel_launch(void* const* d_in, const int* in_sizes, int n_in,
                              void* d_out, int out_size, void* d_ws, size_t ws_size,
                              hipStream_t stream) {
    const float* article  = (const float*)d_in[0];
    const float* question = (const float*)d_in[1];
    const float* options  = (const float*)d_in[2];
    const int*   ans      = (const int*)d_in[3];
    const float* a_Qw = (const float*)d_in[4];  const float* a_Qb = (const float*)d_in[5];
    const float* a_Kw = (const float*)d_in[6];  const float* a_Kb = (const float*)d_in[7];
    const float* a_Vw = (const float*)d_in[8];  const float* a_Vb = (const float*)d_in[9];
    const float* a_vw = (const float*)d_in[10];
    const float* d_Qw = (const float*)d_in[12]; const float* d_Qb = (const float*)d_in[13];
    const float* d_Kw = (const float*)d_in[14]; const float* d_Kb = (const float*)d_in[15];
    const float* d_Vw = (const float*)d_in[16]; const float* d_Vb = (const float*)d_in[17];
    const float* d_vw = (const float*)d_in[18];
    const float* f_w  = (const float*)d_in[20]; const float* f_b  = (const float*)d_in[21];
    float* out = (float*)d_out;

    float* ws = (float*)d_ws;
    float* qp_a  = ws + 32768;       // 32768
    float* aq    = ws + 65536;       // 32768
    float* qp_d  = ws + 98304;       // 32768
    float* feats = ws + 131072;      // 163840
    float* s_art = ws + 294912;      // 65536  (zeroed)
    float* s_opt = ws + 360448;      // 5120   (zeroed)
    float* w_art = ws + 365568;      // 32768  (zeroed)
    float* wd    = ws + 398336;      // 163840 (direct-store, no zero)
    // bf16 region
    __hip_bfloat16* kwa_bf = (__hip_bfloat16*)(ws + 562176);
    __hip_bfloat16* kwd_bf = kwa_bf + 1048576;
    __hip_bfloat16* opt_bf = kwd_bf + 1048576;       // 5242880 elems
    __hip_bfloat16* art_bf = opt_bf + 5242880;       // 67108864 elems

    // K1: all independent init work (conv article first = long pole)
    mega_init_kernel<<<2016, 256, 0, stream>>>(
        article, art_bf, s_art,
        question, ans, a_Qw, a_Qb, qp_a,
        a_Kw, kwa_bf, d_Kw, kwd_bf, options, opt_bf);
    // K2: article score GEMM
    score_mfma8p<<<(NB * LA / 256) * 4, 512, 0, stream>>>(
        art_bf, kwa_bf, a_Kb, qp_a, a_vw, s_art, LA);
    // K3: article softmax
    softmax_kernel<<<NB, 256, 0, stream>>>(s_art, LA);
    // K4: article weighted sum
    wsum_art_v<<<dim3(NB, 8), 256, 0, stream>>>(art_bf, s_art, w_art);
    // K5a: aq = a_Vw * w_art + a_Vb
    proj_kernel<<<dim3(NB, 16), 256, 0, stream>>>(w_art, a_Vw, a_Vb, aq);
    // K5b: qp_d = d_Qw * aq + d_Qb
    proj_kernel<<<dim3(NB, 16), 256, 0, stream>>>(aq, d_Qw, d_Qb, qp_d);
    // K6: option score GEMM
    score_mfma_kernel<<<dim3((NB * 5 * LO) / SBM, HDIM / SBN), 256, 0, stream>>>(
        opt_bf, kwd_bf, d_Kb, qp_d, d_vw, s_opt, 0, 5 * LO);
    // K7: fused option softmax + weighted sum
    wsum_opt_sm<<<NB * 5, 256, 0, stream>>>(opt_bf, s_opt, wd);
    // K8: option V projection -> feats
    proj_kernel<<<dim3(NB * 5, 16), 256, 0, stream>>>(wd, d_Vw, d_Vb, feats);
    // K9: final logits
    final_kernel<<<NB, 256, 0, stream>>>(feats, f_w, f_b, out);
}

// Round 17
// 397.226 us; speedup vs baseline: 1.8994x; 1.0061x over previous
//
#include <hip/hip_runtime.h>
#include <hip/hip_bf16.h>
#include <math.h>

#define HDIM 1024
#define NB 32
#define LA 2048
#define LO 32

typedef __attribute__((ext_vector_type(8))) short bf16x8;
typedef __attribute__((ext_vector_type(4))) float f32x4;
typedef unsigned int u32;

__device__ __forceinline__ float tanh_fast(float x){
    return 2.0f / (1.0f + __expf(-2.0f * x)) - 1.0f;
}

__device__ __forceinline__ void load_lds16(const void* gptr, void* lptr){
    __builtin_amdgcn_global_load_lds(
        (const __attribute__((address_space(1))) u32*)gptr,
        (__attribute__((address_space(3))) u32*)lptr, 16, 0, 0);
}

__device__ __forceinline__ void conv_range(const float* __restrict__ in,
                                           __hip_bfloat16* __restrict__ out,
                                           long n, int nblk, int lb){
    long i = ((long)lb * 256 + threadIdx.x) * 4;
    long stride = (long)nblk * 256 * 4;
    for (; i < n; i += stride){
        float4 v = *(const float4*)(in + i);
        union { __hip_bfloat16 h[4]; short4 s; } u;
        u.h[0] = __float2bfloat16(v.x); u.h[1] = __float2bfloat16(v.y);
        u.h[2] = __float2bfloat16(v.z); u.h[3] = __float2bfloat16(v.w);
        *(short4*)(out + i) = u.s;
    }
}

// ---- mega init: [0,1024) conv article | [1024,1056) zero | [1056,1568) proj_q
//      | [1568,1632) conv a_Kw | [1632,1696) conv d_Kw | [1696,2016) conv options
__global__ __launch_bounds__(256) void mega_init_kernel(
    const float* __restrict__ article, __hip_bfloat16* __restrict__ art_bf,
    float* __restrict__ zbase,
    const float* __restrict__ question, const int* __restrict__ ans,
    const float* __restrict__ a_Qw, const float* __restrict__ a_Qb,
    float* __restrict__ qp_a,
    const float* __restrict__ a_Kw, __hip_bfloat16* __restrict__ kwa_bf,
    const float* __restrict__ d_Kw, __hip_bfloat16* __restrict__ kwd_bf,
    const float* __restrict__ options, __hip_bfloat16* __restrict__ opt_bf)
{
    __shared__ float xin[HDIM];
    int bid = blockIdx.x;
    const int tid = threadIdx.x;
    if (bid < 1024){ conv_range(article, art_bf, 67108864L, 1024, bid); return; }
    bid -= 1024;
    if (bid < 32){
        int i = bid * 256 + tid;
        for (; i < 103424; i += 8192) zbase[i] = 0.f;
        return;
    }
    bid -= 32;
    if (bid < 512){
        const int g = bid >> 4, yq = bid & 15;
        const int lane = tid & 63, wave = tid >> 6;
        const float* in = question + ((size_t)g * 64 + ans[g]) * HDIM;
        *(float4*)&xin[tid * 4] = *(const float4*)&in[tid * 4];
        __syncthreads();
        float4 xv[4];
        #pragma unroll
        for (int c = 0; c < 4; c++) xv[c] = *(const float4*)&xin[(c * 64 + lane) * 4];
        const int hbase = yq * 64 + wave * 16;
        #pragma unroll 4
        for (int r = 0; r < 16; r++){
            int h = hbase + r;
            const float* Wr = a_Qw + (size_t)h * HDIM;
            float p = 0.f;
            #pragma unroll
            for (int c = 0; c < 4; c++){
                float4 wv = *(const float4*)&Wr[(c * 64 + lane) * 4];
                p = fmaf(xv[c].x, wv.x, p); p = fmaf(xv[c].y, wv.y, p);
                p = fmaf(xv[c].z, wv.z, p); p = fmaf(xv[c].w, wv.w, p);
            }
            #pragma unroll
            for (int off = 1; off < 64; off <<= 1) p += __shfl_xor(p, off, 64);
            if (lane == 0) qp_a[(size_t)g * HDIM + h] = p + a_Qb[h];
        }
        return;
    }
    bid -= 512;
    if (bid < 64){ conv_range(a_Kw, kwa_bf, 1048576L, 64, bid); return; }
    bid -= 64;
    if (bid < 64){ conv_range(d_Kw, kwd_bf, 1048576L, 64, bid); return; }
    bid -= 64;
    conv_range(options, opt_bf, 5242880L, 320, bid);
}

// out[g,h] = bias[h] + dot(in[g,:], W[h,:])   grid (G, 16), block 256 (4 waves).
__global__ __launch_bounds__(256) void proj_kernel(
    const float* __restrict__ in, const float* __restrict__ W,
    const float* __restrict__ bias, float* __restrict__ out){
    __shared__ float xin[HDIM];
    const int g = blockIdx.x, tid = threadIdx.x;
    const int lane = tid & 63, wave = tid >> 6;
    *(float4*)&xin[tid * 4] = *(const float4*)&in[(size_t)g * HDIM + tid * 4];
    __syncthreads();
    float4 xv[4];
    #pragma unroll
    for (int c = 0; c < 4; c++) xv[c] = *(const float4*)&xin[(c * 64 + lane) * 4];
    const int hbase = blockIdx.y * 64 + wave * 16;
    #pragma unroll 4
    for (int r = 0; r < 16; r++){
        int h = hbase + r;
        const float* Wr = W + (size_t)h * HDIM;
        float p = 0.f;
        #pragma unroll
        for (int c = 0; c < 4; c++){
            float4 wv = *(const float4*)&Wr[(c * 64 + lane) * 4];
            p = fmaf(xv[c].x, wv.x, p); p = fmaf(xv[c].y, wv.y, p);
            p = fmaf(xv[c].z, wv.z, p); p = fmaf(xv[c].w, wv.w, p);
        }
        #pragma unroll
        for (int off = 1; off < 64; off <<= 1) p += __shfl_xor(p, off, 64);
        if (lane == 0) out[(size_t)g * HDIM + h] = p + bias[h];
    }
}

// ------------- 256h x 256a article score kernel, 16-MFMA phases --------------
// Per 32-k pair: PhA [8 reads; 2-load ISSUE; BAR; lgkm; 16 MFMA hf0-3; BAR]
//                PhB [4 reads; 2-load ISSUE; vmcnt(next); BAR; lgkm; 16 MFMA hf4-7; BAR]
// Arrival of pair k+1 gated in PhB(k) BEFORE a barrier -> PhA(k+1) reads
// collectively safe. Plane (k-1)%4 overwritten in PhA(k) after its leading BAR
// (all pair-k-1 reads lgkm-drained pre-BAR). Ring = 4 planes x 32KB. Tail 8/4/0.
__global__ __launch_bounds__(512, 2) void score_mfma8p(
    const __hip_bfloat16* __restrict__ X, const __hip_bfloat16* __restrict__ Kw,
    const float* __restrict__ Kb, const float* __restrict__ Qp,
    const float* __restrict__ vw, float* __restrict__ s,
    int rows_per_batch)
{
    __shared__ __align__(16) char lds[131072];
    const int tid = threadIdx.x;
    const int lane = tid & 63, wid = tid >> 6;
    const int wm = wid >> 2, wn = wid & 3;
    const int lr = lane & 15, lg = lane >> 4;

    const int na = gridDim.x >> 2;
    const int bid = blockIdx.x;
    const int xcd = bid & 7, seq = bid >> 3;
    const int a_idx = xcd * (na >> 3) + (seq >> 2);
    const int h_idx = seq & 3;
    const int a0 = a_idx * 256, h0 = h_idx * 256;

    f32x4 acc[8][4] = {};
    bf16x8 av[8], bv[4];

    const int rA = tid >> 2;
    const int csw = ((tid & 3) * 16) ^ (((rA >> 1) & 3) << 4);
    const char* pA = (const char*)Kw + (size_t)(h0 + rA) * 2048 + csw;
    const char* pB = (const char*)X  + (size_t)(a0 + rA) * 2048 + csw;
    char* dst0 = lds + tid * 16;

    int aoff[8], boff[4];
    #pragma unroll
    for (int hf = 0; hf < 8; hf++){
        int rw = wm * 128 + hf * 16 + lr;
        aoff[hf] = rw * 64 + ((lg * 16) ^ (((rw >> 1) & 3) << 4));
    }
    #pragma unroll
    for (int af = 0; af < 4; af++){
        int rw = wn * 64 + af * 16 + lr;
        boff[af] = 16384 + rw * 64 + ((lg * 16) ^ (((rw >> 1) & 3) << 4));
    }

#define PBASE(j) ((((j) >> 1) & 1) * 65536 + ((j) & 1) * 32768)
#define PKOFF(j) ((size_t)(((j) >> 1) * 128 + ((j) & 1) * 64))
// full pair issue (prologue): 4 loads
#define ISSUE_PAIR(j) do { \
    load_lds16(pA + PKOFF(j), dst0 + PBASE(j)); \
    load_lds16(pA + PKOFF(j) + 262144, dst0 + PBASE(j) + 8192); \
    load_lds16(pB + PKOFF(j), dst0 + PBASE(j) + 16384); \
    load_lds16(pB + PKOFF(j) + 262144, dst0 + PBASE(j) + 24576); } while(0)
// half issues: A-half then B-half
#define ISSUE_A(j) do { \
    load_lds16(pA + PKOFF(j), dst0 + PBASE(j)); \
    load_lds16(pA + PKOFF(j) + 262144, dst0 + PBASE(j) + 8192); } while(0)
#define ISSUE_B(j) do { \
    load_lds16(pB + PKOFF(j), dst0 + PBASE(j) + 16384); \
    load_lds16(pB + PKOFF(j) + 262144, dst0 + PBASE(j) + 24576); } while(0)

#define WAIT_LGKM() do { \
    asm volatile("s_waitcnt lgkmcnt(0)" ::: "memory"); \
    __builtin_amdgcn_sched_barrier(0); } while(0)
#define BAR() __builtin_amdgcn_s_barrier()

#define MFMA_HALF(H0) do { \
    __builtin_amdgcn_s_setprio(1); \
    _Pragma("unroll") \
    for (int hf = (H0); hf < (H0) + 4; hf++) \
        _Pragma("unroll") \
        for (int af = 0; af < 4; af++) \
            acc[hf][af] = __builtin_amdgcn_mfma_f32_16x16x32_bf16(av[hf], bv[af], acc[hf][af], 0, 0, 0); \
    __builtin_amdgcn_s_setprio(0); } while(0)

// PhA(k): reads av0-3+bv0-3; issue A-half of k+3; BAR; lgkm; MFMA hf0-3; BAR
#define PHASE_A(k, DO_ISSUE) do { \
    const int _b = PBASE(k); \
    _Pragma("unroll") \
    for (int hf = 0; hf < 4; hf++) av[hf] = *(const bf16x8*)(lds + _b + aoff[hf]); \
    _Pragma("unroll") \
    for (int af = 0; af < 4; af++) bv[af] = *(const bf16x8*)(lds + _b + boff[af]); \
    if (DO_ISSUE) ISSUE_A((k) + 3); \
    BAR(); \
    WAIT_LGKM(); \
    MFMA_HALF(0); \
    BAR(); } while(0)

// PhB(k): reads av4-7; issue B-half of k+3; vmcnt(N) guard pair k+1; BAR; lgkm; MFMA hf4-7; BAR
#define PHASE_B(k, DO_ISSUE, VMC) do { \
    const int _b = PBASE(k); \
    _Pragma("unroll") \
    for (int hf = 4; hf < 8; hf++) av[hf] = *(const bf16x8*)(lds + _b + aoff[hf]); \
    if (DO_ISSUE) ISSUE_B((k) + 3); \
    asm volatile("s_waitcnt vmcnt(" #VMC ")" ::: "memory"); \
    BAR(); \
    WAIT_LGKM(); \
    MFMA_HALF(4); \
    BAR(); } while(0)

    // prologue: pairs 0,1,2 fully staged; gate pair 0 collectively
    ISSUE_PAIR(0); ISSUE_PAIR(1); ISSUE_PAIR(2);
    asm volatile("s_waitcnt vmcnt(8)" ::: "memory");
    BAR();

    #pragma unroll 4
    for (int k = 0; k < 28; ++k){
        PHASE_A(k, 1);
        PHASE_B(k, 1, 8);
    }
    PHASE_A(28, 1); PHASE_B(28, 1, 8);   // issues pair 31
    PHASE_A(29, 0); PHASE_B(29, 0, 4);   // guard pair 30
    PHASE_A(30, 0); PHASE_B(30, 0, 0);   // guard pair 31
    PHASE_A(31, 0);
    {   // final half: no guard/issue needed
        const int _b = PBASE(31);
        #pragma unroll
        for (int hf = 4; hf < 8; hf++) av[hf] = *(const bf16x8*)(lds + _b + aoff[hf]);
        WAIT_LGKM();
        MFMA_HALF(4);
    }

    const int b = a0 / rows_per_batch;
    float part[4] = {0.f, 0.f, 0.f, 0.f};
    #pragma unroll
    for (int hf = 0; hf < 8; hf++){
        int hbase = h0 + wm * 128 + hf * 16 + lg * 4;
        float4 kb4 = *(const float4*)(Kb + hbase);
        float4 qp4 = *(const float4*)(Qp + (size_t)b * HDIM + hbase);
        float4 vw4 = *(const float4*)(vw + hbase);
        float q0v = kb4.x + qp4.x, q1v = kb4.y + qp4.y;
        float q2v = kb4.z + qp4.z, q3v = kb4.w + qp4.w;
        #pragma unroll
        for (int af = 0; af < 4; af++){
            part[af] += tanh_fast(acc[hf][af][0] + q0v) * vw4.x;
            part[af] += tanh_fast(acc[hf][af][1] + q1v) * vw4.y;
            part[af] += tanh_fast(acc[hf][af][2] + q2v) * vw4.z;
            part[af] += tanh_fast(acc[hf][af][3] + q3v) * vw4.w;
        }
    }
    #pragma unroll
    for (int af = 0; af < 4; af++){
        float p = part[af];
        p += __shfl_xor(p, 16, 64);
        p += __shfl_xor(p, 32, 64);
        if (lane < 16)
            atomicAdd(&s[a0 + wn * 64 + af * 16 + lr], p);
    }
#undef PBASE
#undef PKOFF
#undef ISSUE_PAIR
#undef ISSUE_A
#undef ISSUE_B
#undef WAIT_LGKM
#undef BAR
#undef MFMA_HALF
#undef PHASE_A
#undef PHASE_B
}

// ---------------- old 128x128 4-wave score kernel (option path) --------------
#define SBM 128
#define SBN 128
__global__ __launch_bounds__(256) void score_mfma_kernel(
    const __hip_bfloat16* __restrict__ X, const __hip_bfloat16* __restrict__ Kw,
    const float* __restrict__ Kb, const float* __restrict__ Qp,
    const float* __restrict__ vw, float* __restrict__ s,
    int row_off, int rows_per_batch)
{
    __shared__ __align__(16) __hip_bfloat16 As[SBM][32];
    __shared__ __align__(16) __hip_bfloat16 Bs[SBN][32];
    const int tid = threadIdx.x;
    const int lane = tid & 63, wid = tid >> 6;
    const int wm = wid >> 1, wn = wid & 1;
    const int row0 = blockIdx.x * SBM;
    const int h0 = blockIdx.y * SBN;
    const int lr = lane & 15, lg = lane >> 4;

    f32x4 acc[4][4] = {};

    for (int k0 = 0; k0 < HDIM; k0 += 32){
        #pragma unroll
        for (int l = 0; l < 2; l++){
            int f = tid + l * 256;
            int r = f >> 2, c8 = (f & 3) * 8;
            load_lds16(X + (size_t)(row0 + r) * HDIM + k0 + c8, &As[0][0] + f * 8);
            load_lds16(Kw + (size_t)(h0 + r) * HDIM + k0 + c8, &Bs[0][0] + f * 8);
        }
        __syncthreads();
        bf16x8 a[4], b[4];
        #pragma unroll
        for (int i = 0; i < 4; i++)
            a[i] = *(const bf16x8*)&As[wm * 64 + i * 16 + lr][lg * 8];
        #pragma unroll
        for (int j = 0; j < 4; j++)
            b[j] = *(const bf16x8*)&Bs[wn * 64 + j * 16 + lr][lg * 8];
        #pragma unroll
        for (int i = 0; i < 4; i++)
            #pragma unroll
            for (int j = 0; j < 4; j++)
                acc[i][j] = __builtin_amdgcn_mfma_f32_16x16x32_bf16(a[i], b[j], acc[i][j], 0, 0, 0);
        __syncthreads();
    }

    float kbv[4], vwv[4];
    #pragma unroll
    for (int j = 0; j < 4; j++){
        int h = h0 + wn * 64 + j * 16 + lr;
        kbv[j] = Kb[h]; vwv[j] = vw[h];
    }
    #pragma unroll
    for (int i = 0; i < 4; i++){
        #pragma unroll
        for (int reg = 0; reg < 4; reg++){
            int r = row0 + wm * 64 + i * 16 + lg * 4 + reg;
            int gr = row_off + r;
            int bb = gr / rows_per_batch;
            const float* Qpb = Qp + (size_t)bb * HDIM;
            float p = 0.f;
            #pragma unroll
            for (int j = 0; j < 4; j++){
                int h = h0 + wn * 64 + j * 16 + lr;
                p += tanh_fast(acc[i][j][reg] + kbv[j] + Qpb[h]) * vwv[j];
            }
            #pragma unroll
            for (int off = 1; off < 16; off <<= 1) p += __shfl_xor(p, off, 16);
            if (lr == 0) atomicAdd(&s[gr], p);
        }
    }
}

// in-place softmax over groups of Rg, grid = G blocks of 256
__global__ void softmax_kernel(float* __restrict__ s, int Rg){
    __shared__ float red[4];
    int g = blockIdx.x, tid = threadIdx.x;
    float* sg = s + (size_t)g * Rg;
    float m = -INFINITY;
    for (int i = tid; i < Rg; i += 256) m = fmaxf(m, sg[i]);
    #pragma unroll
    for (int off = 32; off > 0; off >>= 1) m = fmaxf(m, __shfl_down(m, off, 64));
    if ((tid & 63) == 0) red[tid >> 6] = m;
    __syncthreads();
    m = fmaxf(fmaxf(red[0], red[1]), fmaxf(red[2], red[3]));
    __syncthreads();
    float sum = 0.f;
    for (int i = tid; i < Rg; i += 256){ float e = __expf(sg[i] - m); sg[i] = e; sum += e; }
    #pragma unroll
    for (int off = 32; off > 0; off >>= 1) sum += __shfl_down(sum, off, 64);
    if ((tid & 63) == 0) red[tid >> 6] = sum;
    __syncthreads();
    float inv = 1.0f / (red[0] + red[1] + red[2] + red[3]);
    for (int i = tid; i < Rg; i += 256) sg[i] *= inv;
}

// vectorized bf16 weighted sum (article): grid (NB, 8), 256 thr, short4/thread
__global__ __launch_bounds__(256) void wsum_art_v(
    const __hip_bfloat16* __restrict__ X, const float* __restrict__ sc,
    float* __restrict__ out){
    __shared__ float scs[256];
    const int g = blockIdx.x, ic = blockIdx.y, tid = threadIdx.x;
    scs[tid] = sc[(size_t)g * LA + ic * 256 + tid];
    __syncthreads();
    const __hip_bfloat16* Xg = X + ((size_t)g * LA + ic * 256) * HDIM + tid * 4;
    float a0 = 0.f, a1 = 0.f, a2 = 0.f, a3 = 0.f;
    for (int i = 0; i < 256; i++){
        short4 v = *(const short4*)(Xg + (size_t)i * HDIM);
        float w = scs[i];
        a0 = fmaf(w, __bfloat162float(*(const __hip_bfloat16*)&v.x), a0);
        a1 = fmaf(w, __bfloat162float(*(const __hip_bfloat16*)&v.y), a1);
        a2 = fmaf(w, __bfloat162float(*(const __hip_bfloat16*)&v.z), a2);
        a3 = fmaf(w, __bfloat162float(*(const __hip_bfloat16*)&v.w), a3);
    }
    float* o = out + (size_t)g * HDIM + tid * 4;
    atomicAdd(o + 0, a0); atomicAdd(o + 1, a1);
    atomicAdd(o + 2, a2); atomicAdd(o + 3, a3);
}

// fused 32-softmax + weighted sum (options): grid 160, direct store
__global__ __launch_bounds__(256) void wsum_opt_sm(
    const __hip_bfloat16* __restrict__ X, const float* __restrict__ sraw,
    float* __restrict__ out){
    __shared__ float raw[LO], scs[LO];
    const int g = blockIdx.x, tid = threadIdx.x;
    if (tid < LO) raw[tid] = sraw[(size_t)g * LO + tid];
    __syncthreads();
    float m = -INFINITY;
    #pragma unroll
    for (int i = 0; i < LO; i++) m = fmaxf(m, raw[i]);
    float ssum = 0.f;
    #pragma unroll
    for (int i = 0; i < LO; i++) ssum += __expf(raw[i] - m);
    if (tid < LO) scs[tid] = __expf(raw[tid] - m) / ssum;
    __syncthreads();
    const __hip_bfloat16* Xg = X + (size_t)g * LO * HDIM + tid * 4;
    float a0 = 0.f, a1 = 0.f, a2 = 0.f, a3 = 0.f;
    for (int i = 0; i < LO; i++){
        short4 v = *(const short4*)(Xg + (size_t)i * HDIM);
        float w = scs[i];
        a0 = fmaf(w, __bfloat162float(*(const __hip_bfloat16*)&v.x), a0);
        a1 = fmaf(w, __bfloat162float(*(const __hip_bfloat16*)&v.y), a1);
        a2 = fmaf(w, __bfloat162float(*(const __hip_bfloat16*)&v.z), a2);
        a3 = fmaf(w, __bfloat162float(*(const __hip_bfloat16*)&v.w), a3);
    }
    float* o = out + (size_t)g * HDIM + tid * 4;
    o[0] = a0; o[1] = a1; o[2] = a2; o[3] = a3;
}

// logits[b,j] = fb[j] + dot(feats[b,:5120], fw[j,:5120])  grid 32, block 256
__global__ void final_kernel(const float* __restrict__ feats, const float* __restrict__ fw,
                             const float* __restrict__ fb, float* __restrict__ out){
    __shared__ float red[4];
    int b = blockIdx.x, tid = threadIdx.x;
    const float* fe = feats + (size_t)b * 5120;
    for (int j = 0; j < 5; j++){
        float acc = 0.f;
        for (int i = tid; i < 5120; i += 256) acc += fe[i] * fw[(size_t)j * 5120 + i];
        #pragma unroll
        for (int off = 32; off > 0; off >>= 1) acc += __shfl_down(acc, off, 64);
        if ((tid & 63) == 0) red[tid >> 6] = acc;
        __syncthreads();
        if (tid == 0) out[b * 5 + j] = fb[j] + red[0] + red[1] + red[2] + red[3];
        __syncthreads();
    }
}

extern "C" void kernel_launch(void* const* d_in, const int* in_sizes, int n_in,
                              void* d_out, int out_size, void* d_ws, size_t ws_size,
                              hipStream_t stream) {
    const float* article  = (const float*)d_in[0];
    const float* question = (const float*)d_in[1];
    const float* options  = (const float*)d_in[2];
    const int*   ans      = (const int*)d_in[3];
    const float* a_Qw = (const float*)d_in[4];  const float* a_Qb = (const float*)d_in[5];
    const float* a_Kw = (const float*)d_in[6];  const float* a_Kb = (const float*)d_in[7];
    const float* a_Vw = (const float*)d_in[8];  const float* a_Vb = (const float*)d_in[9];
    const float* a_vw = (const float*)d_in[10];
    const float* d_Qw = (const float*)d_in[12]; const float* d_Qb = (const float*)d_in[13];
    const float* d_Kw = (const float*)d_in[14]; const float* d_Kb = (const float*)d_in[15];
    const float* d_Vw = (const float*)d_in[16]; const float* d_Vb = (const float*)d_in[17];
    const float* d_vw = (const float*)d_in[18];
    const float* f_w  = (const float*)d_in[20]; const float* f_b  = (const float*)d_in[21];
    float* out = (float*)d_out;

    float* ws = (float*)d_ws;
    float* qp_a  = ws + 32768;       // 32768
    float* aq    = ws + 65536;       // 32768
    float* qp_d  = ws + 98304;       // 32768
    float* feats = ws + 131072;      // 163840
    float* s_art = ws + 294912;      // 65536  (zeroed)
    float* s_opt = ws + 360448;      // 5120   (zeroed)
    float* w_art = ws + 365568;      // 32768  (zeroed)
    float* wd    = ws + 398336;      // 163840 (direct-store, no zero)
    // bf16 region
    __hip_bfloat16* kwa_bf = (__hip_bfloat16*)(ws + 562176);
    __hip_bfloat16* kwd_bf = kwa_bf + 1048576;
    __hip_bfloat16* opt_bf = kwd_bf + 1048576;       // 5242880 elems
    __hip_bfloat16* art_bf = opt_bf + 5242880;       // 67108864 elems

    // K1: all independent init work (conv article first = long pole)
    mega_init_kernel<<<2016, 256, 0, stream>>>(
        article, art_bf, s_art,
        question, ans, a_Qw, a_Qb, qp_a,
        a_Kw, kwa_bf, d_Kw, kwd_bf, options, opt_bf);
    // K2: article score GEMM
    score_mfma8p<<<(NB * LA / 256) * 4, 512, 0, stream>>>(
        art_bf, kwa_bf, a_Kb, qp_a, a_vw, s_art, LA);
    // K3: article softmax
    softmax_kernel<<<NB, 256, 0, stream>>>(s_art, LA);
    // K4: article weighted sum
    wsum_art_v<<<dim3(NB, 8), 256, 0, stream>>>(art_bf, s_art, w_art);
    // K5a: aq = a_Vw * w_art + a_Vb
    proj_kernel<<<dim3(NB, 16), 256, 0, stream>>>(w_art, a_Vw, a_Vb, aq);
    // K5b: qp_d = d_Qw * aq + d_Qb
    proj_kernel<<<dim3(NB, 16), 256, 0, stream>>>(aq, d_Qw, d_Qb, qp_d);
    // K6: option score GEMM
    score_mfma_kernel<<<dim3((NB * 5 * LO) / SBM, HDIM / SBN), 256, 0, stream>>>(
        opt_bf, kwd_bf, d_Kb, qp_d, d_vw, s_opt, 0, 5 * LO);
    // K7: fused option softmax + weighted sum
    wsum_opt_sm<<<NB * 5, 256, 0, stream>>>(opt_bf, s_opt, wd);
    // K8: option V projection -> feats
    proj_kernel<<<dim3(NB * 5, 16), 256, 0, stream>>>(wd, d_Vw, d_Vb, feats);
    // K9: final logits
    final_kernel<<<NB, 256, 0, stream>>>(feats, f_w, f_b, out);
}

// Round 18
// 394.676 us; speedup vs baseline: 1.9117x; 1.0065x over previous
//
#include <hip/hip_runtime.h>
#include <hip/hip_bf16.h>
#include <math.h>

#define HDIM 1024
#define NB 32
#define LA 2048
#define LO 32

typedef __attribute__((ext_vector_type(8))) short bf16x8;
typedef __attribute__((ext_vector_type(4))) float f32x4;
typedef unsigned int u32;

__device__ __forceinline__ float tanh_fast(float x){
    return 2.0f / (1.0f + __expf(-2.0f * x)) - 1.0f;
}

__device__ __forceinline__ void load_lds16(const void* gptr, void* lptr){
    __builtin_amdgcn_global_load_lds(
        (const __attribute__((address_space(1))) u32*)gptr,
        (__attribute__((address_space(3))) u32*)lptr, 16, 0, 0);
}

__device__ __forceinline__ void conv_range(const float* __restrict__ in,
                                           __hip_bfloat16* __restrict__ out,
                                           long n, int nblk, int lb){
    long i = ((long)lb * 256 + threadIdx.x) * 4;
    long stride = (long)nblk * 256 * 4;
    for (; i < n; i += stride){
        float4 v = *(const float4*)(in + i);
        union { __hip_bfloat16 h[4]; short4 s; } u;
        u.h[0] = __float2bfloat16(v.x); u.h[1] = __float2bfloat16(v.y);
        u.h[2] = __float2bfloat16(v.z); u.h[3] = __float2bfloat16(v.w);
        *(short4*)(out + i) = u.s;
    }
}

// ---- mega init: [0,1024) conv article | [1024,1056) zero | [1056,1568) proj_q
//      | [1568,1632) conv a_Kw | [1632,1696) conv d_Kw | [1696,2016) conv options
__global__ __launch_bounds__(256) void mega_init_kernel(
    const float* __restrict__ article, __hip_bfloat16* __restrict__ art_bf,
    float* __restrict__ zbase,
    const float* __restrict__ question, const int* __restrict__ ans,
    const float* __restrict__ a_Qw, const float* __restrict__ a_Qb,
    float* __restrict__ qp_a,
    const float* __restrict__ a_Kw, __hip_bfloat16* __restrict__ kwa_bf,
    const float* __restrict__ d_Kw, __hip_bfloat16* __restrict__ kwd_bf,
    const float* __restrict__ options, __hip_bfloat16* __restrict__ opt_bf)
{
    __shared__ float xin[HDIM];
    int bid = blockIdx.x;
    const int tid = threadIdx.x;
    if (bid < 1024){ conv_range(article, art_bf, 67108864L, 1024, bid); return; }
    bid -= 1024;
    if (bid < 32){
        int i = bid * 256 + tid;
        for (; i < 103424; i += 8192) zbase[i] = 0.f;
        return;
    }
    bid -= 32;
    if (bid < 512){
        const int g = bid >> 4, yq = bid & 15;
        const int lane = tid & 63, wave = tid >> 6;
        const float* in = question + ((size_t)g * 64 + ans[g]) * HDIM;
        *(float4*)&xin[tid * 4] = *(const float4*)&in[tid * 4];
        __syncthreads();
        float4 xv[4];
        #pragma unroll
        for (int c = 0; c < 4; c++) xv[c] = *(const float4*)&xin[(c * 64 + lane) * 4];
        const int hbase = yq * 64 + wave * 16;
        #pragma unroll 4
        for (int r = 0; r < 16; r++){
            int h = hbase + r;
            const float* Wr = a_Qw + (size_t)h * HDIM;
            float p = 0.f;
            #pragma unroll
            for (int c = 0; c < 4; c++){
                float4 wv = *(const float4*)&Wr[(c * 64 + lane) * 4];
                p = fmaf(xv[c].x, wv.x, p); p = fmaf(xv[c].y, wv.y, p);
                p = fmaf(xv[c].z, wv.z, p); p = fmaf(xv[c].w, wv.w, p);
            }
            #pragma unroll
            for (int off = 1; off < 64; off <<= 1) p += __shfl_xor(p, off, 64);
            if (lane == 0) qp_a[(size_t)g * HDIM + h] = p + a_Qb[h];
        }
        return;
    }
    bid -= 512;
    if (bid < 64){ conv_range(a_Kw, kwa_bf, 1048576L, 64, bid); return; }
    bid -= 64;
    if (bid < 64){ conv_range(d_Kw, kwd_bf, 1048576L, 64, bid); return; }
    bid -= 64;
    conv_range(options, opt_bf, 5242880L, 320, bid);
}

// out[g,h] = bias[h] + dot(in[g,:], W[h,:])   grid (G, 16), block 256 (4 waves).
__global__ __launch_bounds__(256) void proj_kernel(
    const float* __restrict__ in, const float* __restrict__ W,
    const float* __restrict__ bias, float* __restrict__ out){
    __shared__ float xin[HDIM];
    const int g = blockIdx.x, tid = threadIdx.x;
    const int lane = tid & 63, wave = tid >> 6;
    *(float4*)&xin[tid * 4] = *(const float4*)&in[(size_t)g * HDIM + tid * 4];
    __syncthreads();
    float4 xv[4];
    #pragma unroll
    for (int c = 0; c < 4; c++) xv[c] = *(const float4*)&xin[(c * 64 + lane) * 4];
    const int hbase = blockIdx.y * 64 + wave * 16;
    #pragma unroll 4
    for (int r = 0; r < 16; r++){
        int h = hbase + r;
        const float* Wr = W + (size_t)h * HDIM;
        float p = 0.f;
        #pragma unroll
        for (int c = 0; c < 4; c++){
            float4 wv = *(const float4*)&Wr[(c * 64 + lane) * 4];
            p = fmaf(xv[c].x, wv.x, p); p = fmaf(xv[c].y, wv.y, p);
            p = fmaf(xv[c].z, wv.z, p); p = fmaf(xv[c].w, wv.w, p);
        }
        #pragma unroll
        for (int off = 1; off < 64; off <<= 1) p += __shfl_xor(p, off, 64);
        if (lane == 0) out[(size_t)g * HDIM + h] = p + bias[h];
    }
}

// ------------- 256h x 256a article score kernel, 16-MFMA phases (R17) --------
__global__ __launch_bounds__(512, 2) void score_mfma8p(
    const __hip_bfloat16* __restrict__ X, const __hip_bfloat16* __restrict__ Kw,
    const float* __restrict__ Kb, const float* __restrict__ Qp,
    const float* __restrict__ vw, float* __restrict__ s,
    int rows_per_batch)
{
    __shared__ __align__(16) char lds[131072];
    const int tid = threadIdx.x;
    const int lane = tid & 63, wid = tid >> 6;
    const int wm = wid >> 2, wn = wid & 3;
    const int lr = lane & 15, lg = lane >> 4;

    const int na = gridDim.x >> 2;
    const int bid = blockIdx.x;
    const int xcd = bid & 7, seq = bid >> 3;
    const int a_idx = xcd * (na >> 3) + (seq >> 2);
    const int h_idx = seq & 3;
    const int a0 = a_idx * 256, h0 = h_idx * 256;

    f32x4 acc[8][4] = {};
    bf16x8 av[8], bv[4];

    const int rA = tid >> 2;
    const int csw = ((tid & 3) * 16) ^ (((rA >> 1) & 3) << 4);
    const char* pA = (const char*)Kw + (size_t)(h0 + rA) * 2048 + csw;
    const char* pB = (const char*)X  + (size_t)(a0 + rA) * 2048 + csw;
    char* dst0 = lds + tid * 16;

    int aoff[8], boff[4];
    #pragma unroll
    for (int hf = 0; hf < 8; hf++){
        int rw = wm * 128 + hf * 16 + lr;
        aoff[hf] = rw * 64 + ((lg * 16) ^ (((rw >> 1) & 3) << 4));
    }
    #pragma unroll
    for (int af = 0; af < 4; af++){
        int rw = wn * 64 + af * 16 + lr;
        boff[af] = 16384 + rw * 64 + ((lg * 16) ^ (((rw >> 1) & 3) << 4));
    }

#define PBASE(j) ((((j) >> 1) & 1) * 65536 + ((j) & 1) * 32768)
#define PKOFF(j) ((size_t)(((j) >> 1) * 128 + ((j) & 1) * 64))
#define ISSUE_PAIR(j) do { \
    load_lds16(pA + PKOFF(j), dst0 + PBASE(j)); \
    load_lds16(pA + PKOFF(j) + 262144, dst0 + PBASE(j) + 8192); \
    load_lds16(pB + PKOFF(j), dst0 + PBASE(j) + 16384); \
    load_lds16(pB + PKOFF(j) + 262144, dst0 + PBASE(j) + 24576); } while(0)
#define ISSUE_A(j) do { \
    load_lds16(pA + PKOFF(j), dst0 + PBASE(j)); \
    load_lds16(pA + PKOFF(j) + 262144, dst0 + PBASE(j) + 8192); } while(0)
#define ISSUE_B(j) do { \
    load_lds16(pB + PKOFF(j), dst0 + PBASE(j) + 16384); \
    load_lds16(pB + PKOFF(j) + 262144, dst0 + PBASE(j) + 24576); } while(0)

#define WAIT_LGKM() do { \
    asm volatile("s_waitcnt lgkmcnt(0)" ::: "memory"); \
    __builtin_amdgcn_sched_barrier(0); } while(0)
#define BAR() __builtin_amdgcn_s_barrier()

#define MFMA_HALF(H0) do { \
    __builtin_amdgcn_s_setprio(1); \
    _Pragma("unroll") \
    for (int hf = (H0); hf < (H0) + 4; hf++) \
        _Pragma("unroll") \
        for (int af = 0; af < 4; af++) \
            acc[hf][af] = __builtin_amdgcn_mfma_f32_16x16x32_bf16(av[hf], bv[af], acc[hf][af], 0, 0, 0); \
    __builtin_amdgcn_s_setprio(0); } while(0)

#define PHASE_A(k, DO_ISSUE) do { \
    const int _b = PBASE(k); \
    _Pragma("unroll") \
    for (int hf = 0; hf < 4; hf++) av[hf] = *(const bf16x8*)(lds + _b + aoff[hf]); \
    _Pragma("unroll") \
    for (int af = 0; af < 4; af++) bv[af] = *(const bf16x8*)(lds + _b + boff[af]); \
    if (DO_ISSUE) ISSUE_A((k) + 3); \
    BAR(); \
    WAIT_LGKM(); \
    MFMA_HALF(0); \
    BAR(); } while(0)

#define PHASE_B(k, DO_ISSUE, VMC) do { \
    const int _b = PBASE(k); \
    _Pragma("unroll") \
    for (int hf = 4; hf < 8; hf++) av[hf] = *(const bf16x8*)(lds + _b + aoff[hf]); \
    if (DO_ISSUE) ISSUE_B((k) + 3); \
    asm volatile("s_waitcnt vmcnt(" #VMC ")" ::: "memory"); \
    BAR(); \
    WAIT_LGKM(); \
    MFMA_HALF(4); \
    BAR(); } while(0)

    ISSUE_PAIR(0); ISSUE_PAIR(1); ISSUE_PAIR(2);
    asm volatile("s_waitcnt vmcnt(8)" ::: "memory");
    BAR();

    #pragma unroll 4
    for (int k = 0; k < 28; ++k){
        PHASE_A(k, 1);
        PHASE_B(k, 1, 8);
    }
    PHASE_A(28, 1); PHASE_B(28, 1, 8);
    PHASE_A(29, 0); PHASE_B(29, 0, 4);
    PHASE_A(30, 0); PHASE_B(30, 0, 0);
    PHASE_A(31, 0);
    {
        const int _b = PBASE(31);
        #pragma unroll
        for (int hf = 4; hf < 8; hf++) av[hf] = *(const bf16x8*)(lds + _b + aoff[hf]);
        WAIT_LGKM();
        MFMA_HALF(4);
    }

    const int b = a0 / rows_per_batch;
    float part[4] = {0.f, 0.f, 0.f, 0.f};
    #pragma unroll
    for (int hf = 0; hf < 8; hf++){
        int hbase = h0 + wm * 128 + hf * 16 + lg * 4;
        float4 kb4 = *(const float4*)(Kb + hbase);
        float4 qp4 = *(const float4*)(Qp + (size_t)b * HDIM + hbase);
        float4 vw4 = *(const float4*)(vw + hbase);
        float q0v = kb4.x + qp4.x, q1v = kb4.y + qp4.y;
        float q2v = kb4.z + qp4.z, q3v = kb4.w + qp4.w;
        #pragma unroll
        for (int af = 0; af < 4; af++){
            part[af] += tanh_fast(acc[hf][af][0] + q0v) * vw4.x;
            part[af] += tanh_fast(acc[hf][af][1] + q1v) * vw4.y;
            part[af] += tanh_fast(acc[hf][af][2] + q2v) * vw4.z;
            part[af] += tanh_fast(acc[hf][af][3] + q3v) * vw4.w;
        }
    }
    #pragma unroll
    for (int af = 0; af < 4; af++){
        float p = part[af];
        p += __shfl_xor(p, 16, 64);
        p += __shfl_xor(p, 32, 64);
        if (lane < 16)
            atomicAdd(&s[a0 + wn * 64 + af * 16 + lr], p);
    }
#undef PBASE
#undef PKOFF
#undef ISSUE_PAIR
#undef ISSUE_A
#undef ISSUE_B
#undef WAIT_LGKM
#undef BAR
#undef MFMA_HALF
#undef PHASE_A
#undef PHASE_B
}

// ---------------- old 128x128 4-wave score kernel (option path) --------------
#define SBM 128
#define SBN 128
__global__ __launch_bounds__(256) void score_mfma_kernel(
    const __hip_bfloat16* __restrict__ X, const __hip_bfloat16* __restrict__ Kw,
    const float* __restrict__ Kb, const float* __restrict__ Qp,
    const float* __restrict__ vw, float* __restrict__ s,
    int row_off, int rows_per_batch)
{
    __shared__ __align__(16) __hip_bfloat16 As[SBM][32];
    __shared__ __align__(16) __hip_bfloat16 Bs[SBN][32];
    const int tid = threadIdx.x;
    const int lane = tid & 63, wid = tid >> 6;
    const int wm = wid >> 1, wn = wid & 1;
    const int row0 = blockIdx.x * SBM;
    const int h0 = blockIdx.y * SBN;
    const int lr = lane & 15, lg = lane >> 4;

    f32x4 acc[4][4] = {};

    for (int k0 = 0; k0 < HDIM; k0 += 32){
        #pragma unroll
        for (int l = 0; l < 2; l++){
            int f = tid + l * 256;
            int r = f >> 2, c8 = (f & 3) * 8;
            load_lds16(X + (size_t)(row0 + r) * HDIM + k0 + c8, &As[0][0] + f * 8);
            load_lds16(Kw + (size_t)(h0 + r) * HDIM + k0 + c8, &Bs[0][0] + f * 8);
        }
        __syncthreads();
        bf16x8 a[4], b[4];
        #pragma unroll
        for (int i = 0; i < 4; i++)
            a[i] = *(const bf16x8*)&As[wm * 64 + i * 16 + lr][lg * 8];
        #pragma unroll
        for (int j = 0; j < 4; j++)
            b[j] = *(const bf16x8*)&Bs[wn * 64 + j * 16 + lr][lg * 8];
        #pragma unroll
        for (int i = 0; i < 4; i++)
            #pragma unroll
            for (int j = 0; j < 4; j++)
                acc[i][j] = __builtin_amdgcn_mfma_f32_16x16x32_bf16(a[i], b[j], acc[i][j], 0, 0, 0);
        __syncthreads();
    }

    float kbv[4], vwv[4];
    #pragma unroll
    for (int j = 0; j < 4; j++){
        int h = h0 + wn * 64 + j * 16 + lr;
        kbv[j] = Kb[h]; vwv[j] = vw[h];
    }
    #pragma unroll
    for (int i = 0; i < 4; i++){
        #pragma unroll
        for (int reg = 0; reg < 4; reg++){
            int r = row0 + wm * 64 + i * 16 + lg * 4 + reg;
            int gr = row_off + r;
            int bb = gr / rows_per_batch;
            const float* Qpb = Qp + (size_t)bb * HDIM;
            float p = 0.f;
            #pragma unroll
            for (int j = 0; j < 4; j++){
                int h = h0 + wn * 64 + j * 16 + lr;
                p += tanh_fast(acc[i][j][reg] + kbv[j] + Qpb[h]) * vwv[j];
            }
            #pragma unroll
            for (int off = 1; off < 16; off <<= 1) p += __shfl_xor(p, off, 16);
            if (lr == 0) atomicAdd(&s[gr], p);
        }
    }
}

// fused 2048-softmax + weighted sum (article): grid (NB, 8), 256 thr.
// Each block redundantly computes the batch softmax stats (8 KB read), then
// weighted-sums its 256-row chunk with short4 loads; atomicAdd into out.
__global__ __launch_bounds__(256) void wsum_art_sm(
    const __hip_bfloat16* __restrict__ X, const float* __restrict__ sraw,
    float* __restrict__ out){
    __shared__ float red[4];
    __shared__ float scs[256];
    const int g = blockIdx.x, ic = blockIdx.y, tid = threadIdx.x;
    const float* sg = sraw + (size_t)g * LA;
    float4 v0 = *(const float4*)&sg[tid * 8];
    float4 v1 = *(const float4*)&sg[tid * 8 + 4];
    float m = fmaxf(fmaxf(fmaxf(v0.x, v0.y), fmaxf(v0.z, v0.w)),
                    fmaxf(fmaxf(v1.x, v1.y), fmaxf(v1.z, v1.w)));
    #pragma unroll
    for (int off = 32; off > 0; off >>= 1) m = fmaxf(m, __shfl_down(m, off, 64));
    if ((tid & 63) == 0) red[tid >> 6] = m;
    __syncthreads();
    m = fmaxf(fmaxf(red[0], red[1]), fmaxf(red[2], red[3]));
    __syncthreads();
    float sum = __expf(v0.x - m) + __expf(v0.y - m) + __expf(v0.z - m) + __expf(v0.w - m)
              + __expf(v1.x - m) + __expf(v1.y - m) + __expf(v1.z - m) + __expf(v1.w - m);
    #pragma unroll
    for (int off = 32; off > 0; off >>= 1) sum += __shfl_down(sum, off, 64);
    if ((tid & 63) == 0) red[tid >> 6] = sum;
    __syncthreads();
    float inv = 1.0f / (red[0] + red[1] + red[2] + red[3]);
    scs[tid] = __expf(sg[ic * 256 + tid] - m) * inv;
    __syncthreads();
    const __hip_bfloat16* Xg = X + ((size_t)g * LA + ic * 256) * HDIM + tid * 4;
    float a0 = 0.f, a1 = 0.f, a2 = 0.f, a3 = 0.f;
    for (int i = 0; i < 256; i++){
        short4 v = *(const short4*)(Xg + (size_t)i * HDIM);
        float w = scs[i];
        a0 = fmaf(w, __bfloat162float(*(const __hip_bfloat16*)&v.x), a0);
        a1 = fmaf(w, __bfloat162float(*(const __hip_bfloat16*)&v.y), a1);
        a2 = fmaf(w, __bfloat162float(*(const __hip_bfloat16*)&v.z), a2);
        a3 = fmaf(w, __bfloat162float(*(const __hip_bfloat16*)&v.w), a3);
    }
    float* o = out + (size_t)g * HDIM + tid * 4;
    atomicAdd(o + 0, a0); atomicAdd(o + 1, a1);
    atomicAdd(o + 2, a2); atomicAdd(o + 3, a3);
}

// fused 32-softmax + weighted sum (options): grid 160, direct store
__global__ __launch_bounds__(256) void wsum_opt_sm(
    const __hip_bfloat16* __restrict__ X, const float* __restrict__ sraw,
    float* __restrict__ out){
    __shared__ float raw[LO], scs[LO];
    const int g = blockIdx.x, tid = threadIdx.x;
    if (tid < LO) raw[tid] = sraw[(size_t)g * LO + tid];
    __syncthreads();
    float m = -INFINITY;
    #pragma unroll
    for (int i = 0; i < LO; i++) m = fmaxf(m, raw[i]);
    float ssum = 0.f;
    #pragma unroll
    for (int i = 0; i < LO; i++) ssum += __expf(raw[i] - m);
    if (tid < LO) scs[tid] = __expf(raw[tid] - m) / ssum;
    __syncthreads();
    const __hip_bfloat16* Xg = X + (size_t)g * LO * HDIM + tid * 4;
    float a0 = 0.f, a1 = 0.f, a2 = 0.f, a3 = 0.f;
    for (int i = 0; i < LO; i++){
        short4 v = *(const short4*)(Xg + (size_t)i * HDIM);
        float w = scs[i];
        a0 = fmaf(w, __bfloat162float(*(const __hip_bfloat16*)&v.x), a0);
        a1 = fmaf(w, __bfloat162float(*(const __hip_bfloat16*)&v.y), a1);
        a2 = fmaf(w, __bfloat162float(*(const __hip_bfloat16*)&v.z), a2);
        a3 = fmaf(w, __bfloat162float(*(const __hip_bfloat16*)&v.w), a3);
    }
    float* o = out + (size_t)g * HDIM + tid * 4;
    o[0] = a0; o[1] = a1; o[2] = a2; o[3] = a3;
}

// logits[b,j] = fb[j] + dot(feats[b,:5120], fw[j,:5120])  grid 32, block 256
__global__ void final_kernel(const float* __restrict__ feats, const float* __restrict__ fw,
                             const float* __restrict__ fb, float* __restrict__ out){
    __shared__ float red[4];
    int b = blockIdx.x, tid = threadIdx.x;
    const float* fe = feats + (size_t)b * 5120;
    for (int j = 0; j < 5; j++){
        float acc = 0.f;
        for (int i = tid; i < 5120; i += 256) acc += fe[i] * fw[(size_t)j * 5120 + i];
        #pragma unroll
        for (int off = 32; off > 0; off >>= 1) acc += __shfl_down(acc, off, 64);
        if ((tid & 63) == 0) red[tid >> 6] = acc;
        __syncthreads();
        if (tid == 0) out[b * 5 + j] = fb[j] + red[0] + red[1] + red[2] + red[3];
        __syncthreads();
    }
}

extern "C" void kernel_launch(void* const* d_in, const int* in_sizes, int n_in,
                              void* d_out, int out_size, void* d_ws, size_t ws_size,
                              hipStream_t stream) {
    const float* article  = (const float*)d_in[0];
    const float* question = (const float*)d_in[1];
    const float* options  = (const float*)d_in[2];
    const int*   ans      = (const int*)d_in[3];
    const float* a_Qw = (const float*)d_in[4];  const float* a_Qb = (const float*)d_in[5];
    const float* a_Kw = (const float*)d_in[6];  const float* a_Kb = (const float*)d_in[7];
    const float* a_Vw = (const float*)d_in[8];  const float* a_Vb = (const float*)d_in[9];
    const float* a_vw = (const float*)d_in[10];
    const float* d_Qw = (const float*)d_in[12]; const float* d_Qb = (const float*)d_in[13];
    const float* d_Kw = (const float*)d_in[14]; const float* d_Kb = (const float*)d_in[15];
    const float* d_Vw = (const float*)d_in[16]; const float* d_Vb = (const float*)d_in[17];
    const float* d_vw = (const float*)d_in[18];
    const float* f_w  = (const float*)d_in[20]; const float* f_b  = (const float*)d_in[21];
    float* out = (float*)d_out;

    float* ws = (float*)d_ws;
    float* qp_a  = ws + 32768;       // 32768
    float* aq    = ws + 65536;       // 32768
    float* qp_d  = ws + 98304;       // 32768
    float* feats = ws + 131072;      // 163840
    float* s_art = ws + 294912;      // 65536  (zeroed)
    float* s_opt = ws + 360448;      // 5120   (zeroed)
    float* w_art = ws + 365568;      // 32768  (zeroed)
    float* wd    = ws + 398336;      // 163840 (direct-store, no zero)
    // bf16 region
    __hip_bfloat16* kwa_bf = (__hip_bfloat16*)(ws + 562176);
    __hip_bfloat16* kwd_bf = kwa_bf + 1048576;
    __hip_bfloat16* opt_bf = kwd_bf + 1048576;       // 5242880 elems
    __hip_bfloat16* art_bf = opt_bf + 5242880;       // 67108864 elems

    // K1: all independent init work (conv article first = long pole)
    mega_init_kernel<<<2016, 256, 0, stream>>>(
        article, art_bf, s_art,
        question, ans, a_Qw, a_Qb, qp_a,
        a_Kw, kwa_bf, d_Kw, kwd_bf, options, opt_bf);
    // K2: article score GEMM
    score_mfma8p<<<(NB * LA / 256) * 4, 512, 0, stream>>>(
        art_bf, kwa_bf, a_Kb, qp_a, a_vw, s_art, LA);
    // K3: fused article softmax + weighted sum
    wsum_art_sm<<<dim3(NB, 8), 256, 0, stream>>>(art_bf, s_art, w_art);
    // K4a: aq = a_Vw * w_art + a_Vb
    proj_kernel<<<dim3(NB, 16), 256, 0, stream>>>(w_art, a_Vw, a_Vb, aq);
    // K4b: qp_d = d_Qw * aq + d_Qb
    proj_kernel<<<dim3(NB, 16), 256, 0, stream>>>(aq, d_Qw, d_Qb, qp_d);
    // K5: option score GEMM
    score_mfma_kernel<<<dim3((NB * 5 * LO) / SBM, HDIM / SBN), 256, 0, stream>>>(
        opt_bf, kwd_bf, d_Kb, qp_d, d_vw, s_opt, 0, 5 * LO);
    // K6: fused option softmax + weighted sum
    wsum_opt_sm<<<NB * 5, 256, 0, stream>>>(opt_bf, s_opt, wd);
    // K7: option V projection -> feats
    proj_kernel<<<dim3(NB * 5, 16), 256, 0, stream>>>(wd, d_Vw, d_Vb, feats);
    // K8: final logits
    final_kernel<<<NB, 256, 0, stream>>>(feats, f_w, f_b, out);
}